// Round 10
// baseline (417.508 us; speedup 1.0000x reference)
//
#include <hip/hip_runtime.h>
#include <cstdint>
#include <cstddef>

// Problem constants
#define LSEQ 4096
#define DM 1024
#define DI 2048
#define DCONV 4
#define DRNK 64
#define DSTATE 16
#define DXW 96        // DRNK + 2*DSTATE
#define NCH 64
#define CLEN 64       // LSEQ / NCH
#define KSPLIT 8      // split-K for dbl GEMM

typedef unsigned short ushort_t;
typedef __bf16 bfx8 __attribute__((ext_vector_type(8)));
typedef float  fx4  __attribute__((ext_vector_type(4)));
typedef ushort_t usx8 __attribute__((ext_vector_type(8)));

__device__ __forceinline__ float siluf(float x) { return x / (1.f + __expf(-x)); }
__device__ __forceinline__ float softplusf(float x) {
  return fmaxf(x, 0.f) + log1pf(__expf(-fabsf(x)));
}
__device__ __forceinline__ ushort_t f2b(float x) {
  __bf16 b = (__bf16)x;   // RNE
  return __builtin_bit_cast(ushort_t, b);
}
__device__ __forceinline__ float b2f(ushort_t u) {
  unsigned int x = ((unsigned int)u) << 16;
  return __builtin_bit_cast(float, x);
}
__device__ __forceinline__ void async16(const void* g, void* l) {
  __builtin_amdgcn_global_load_lds(
      (const __attribute__((address_space(1))) unsigned int*)g,
      (__attribute__((address_space(3))) unsigned int*)l, 16, 0, 0);
}

// ---------------------------------------------------------------------------
// bf16 MFMA NT GEMM: 128xBN tile (BN=128 or 64), BK=32, 4 waves 2x2.
// XOR-swizzled LDS (conflict-free, r5: SQ_LDS_BANK_CONFLICT=0).
// EPI: 0 = f32 store, 1 = bf16 store, 2 = bf16 store of softplus(acc+bias[n]).
// NOTE (r6): 128x256 tile regressed (occupancy 10%, 89us vs 60us).
// NOTE (r8): cooperative grid-sync scan fusion regressed 3x.
// ---------------------------------------------------------------------------
template <int EPI, int BN>
__global__ __launch_bounds__(256) void gemm_bf16(
    const ushort_t* __restrict__ A, int lda,
    const ushort_t* __restrict__ B, int ldb,
    void* __restrict__ Cv, int ldc, int K,
    const float* __restrict__ bias)
{
  constexpr int NJ = BN / 32;
  __shared__ ushort_t As[128 * 32];
  __shared__ ushort_t Bs[BN * 32];
  const int tid  = threadIdx.x;
  const int m0   = blockIdx.y * 128, n0 = blockIdx.x * BN;
  const int lane = tid & 63;
  const int wave = tid >> 6;
  const int wm   = (wave >> 1) * 64, wn = (wave & 1) * (BN / 2);
  const int lm   = lane & 15;
  const int r0 = tid >> 2;
  const int cswz = (((tid & 3) ^ ((r0 >> 1) & 3))) * 8;
  const int swz = (((lane >> 4) ^ ((lm >> 1) & 3))) * 8;

  fx4 acc[4][NJ] = {};

  const ushort_t* ga = A + (size_t)(m0 + r0) * lda + cswz;
  const ushort_t* gb = B + (size_t)(n0 + r0) * ldb + cswz;
  ushort_t* la0 = &As[r0 * 32 + (tid & 3) * 8];
  ushort_t* la1 = &As[(r0 + 64) * 32 + (tid & 3) * 8];
  ushort_t* lb0 = &Bs[r0 * 32 + (tid & 3) * 8];
  ushort_t* lb1 = (BN == 128) ? &Bs[(r0 + 64) * 32 + (tid & 3) * 8] : nullptr;

  for (int k0 = 0; k0 < K; k0 += 32) {
    async16(ga + k0, la0);
    async16(ga + (size_t)64 * lda + k0, la1);
    async16(gb + k0, lb0);
    if (BN == 128) async16(gb + (size_t)64 * ldb + k0, lb1);
    __syncthreads();

    bfx8 af[4], bfr[NJ];
#pragma unroll
    for (int i = 0; i < 4; ++i)
      af[i] = *(const bfx8*)&As[(wm + i * 16 + lm) * 32 + swz];
#pragma unroll
    for (int j = 0; j < NJ; ++j)
      bfr[j] = *(const bfx8*)&Bs[(wn + j * 16 + lm) * 32 + swz];
#pragma unroll
    for (int i = 0; i < 4; ++i)
#pragma unroll
      for (int j = 0; j < NJ; ++j)
        acc[i][j] = __builtin_amdgcn_mfma_f32_16x16x32_bf16(af[i], bfr[j], acc[i][j], 0, 0, 0);
    __syncthreads();
  }

  // C/D layout (16x16): col = lane&15, row = (lane>>4)*4 + reg
  const int crow = (lane >> 4) * 4;
  const int ccol = lane & 15;
#pragma unroll
  for (int i = 0; i < 4; ++i)
#pragma unroll
    for (int r = 0; r < 4; ++r) {
      const size_t rowoff = (size_t)(m0 + wm + i * 16 + crow + r) * ldc + n0 + wn + ccol;
      if (EPI == 1) {
        ushort_t* cp = (ushort_t*)Cv + rowoff;
#pragma unroll
        for (int j = 0; j < NJ; ++j) cp[j * 16] = f2b(acc[i][j][r]);
      } else if (EPI == 2) {
        ushort_t* cp = (ushort_t*)Cv + rowoff;
        const int nb = n0 + wn + ccol;
#pragma unroll
        for (int j = 0; j < NJ; ++j)
          cp[j * 16] = f2b(softplusf(acc[i][j][r] + bias[nb + j * 16]));
      } else {
        float* cp = (float*)Cv + rowoff;
#pragma unroll
        for (int j = 0; j < NJ; ++j) cp[j * 16] = acc[i][j][r];
      }
    }
}

// ---------------------------------------------------------------------------
// dbl GEMM: partial[z][L,96] f32 = xsb[L,2048]bf16 @ W_xb[96,2048]bf16^T
// over K-chunk z (KSPLIT=8 -> 256-wide chunks). Plain stores (no atomics).
// ---------------------------------------------------------------------------
__global__ __launch_bounds__(256) void gemm_dbl(
    const ushort_t* __restrict__ A, const ushort_t* __restrict__ B,
    float* __restrict__ P)
{
  __shared__ ushort_t As[128 * 32];
  __shared__ ushort_t Bs[128 * 32];
  const int tid  = threadIdx.x;
  const int m0   = blockIdx.y * 128;
  const int lane = tid & 63;
  const int wave = tid >> 6;
  const int wm   = (wave >> 1) * 64, wn = (wave & 1) * 48;
  const int lm   = lane & 15;
  const int r0 = tid >> 2;
  const int cswz = (((tid & 3) ^ ((r0 >> 1) & 3))) * 8;
  const int swz  = (((lane >> 4) ^ ((lm >> 1) & 3))) * 8;
  const int kbeg = blockIdx.z * (DI / KSPLIT);

  fx4 acc[4][3] = {};

  const int brow1 = (r0 + 64 < DXW) ? r0 + 64 : DXW - 1;  // clamp; rows>=96 unused
  const ushort_t* ga  = A + (size_t)(m0 + r0) * DI + kbeg + cswz;
  const ushort_t* gb0 = B + (size_t)r0 * DI + kbeg + cswz;
  const ushort_t* gb1 = B + (size_t)brow1 * DI + kbeg + cswz;
  ushort_t* la0 = &As[r0 * 32 + (tid & 3) * 8];
  ushort_t* la1 = &As[(r0 + 64) * 32 + (tid & 3) * 8];
  ushort_t* lb0 = &Bs[r0 * 32 + (tid & 3) * 8];
  ushort_t* lb1 = &Bs[(r0 + 64) * 32 + (tid & 3) * 8];

  for (int k0 = 0; k0 < DI / KSPLIT; k0 += 32) {
    async16(ga + k0, la0);
    async16(ga + (size_t)64 * DI + k0, la1);
    async16(gb0 + k0, lb0);
    async16(gb1 + k0, lb1);
    __syncthreads();

    bfx8 af[4], bfr[3];
#pragma unroll
    for (int i = 0; i < 4; ++i)
      af[i] = *(const bfx8*)&As[(wm + i * 16 + lm) * 32 + swz];
#pragma unroll
    for (int j = 0; j < 3; ++j)
      bfr[j] = *(const bfx8*)&Bs[(wn + j * 16 + lm) * 32 + swz];
#pragma unroll
    for (int i = 0; i < 4; ++i)
#pragma unroll
      for (int j = 0; j < 3; ++j)
        acc[i][j] = __builtin_amdgcn_mfma_f32_16x16x32_bf16(af[i], bfr[j], acc[i][j], 0, 0, 0);
    __syncthreads();
  }

  float* base = P + (size_t)blockIdx.z * LSEQ * DXW;
  const int crow = (lane >> 4) * 4;
  const int ccol = lane & 15;
#pragma unroll
  for (int i = 0; i < 4; ++i)
#pragma unroll
    for (int r = 0; r < 4; ++r) {
      float* cp = base + (size_t)(m0 + wm + i * 16 + crow + r) * DXW + wn + ccol;
#pragma unroll
      for (int j = 0; j < 3; ++j)
        cp[j * 16] = acc[i][j][r];
    }
}

// ---------------------------------------------------------------------------
// reduce_dbl: sum KSPLIT partials; emit dtb = bf16(cols 0..63) and
// dblBC = f32 compact (cols 64..95 -> [l][32]). Deterministic z-order.
// ---------------------------------------------------------------------------
__global__ __launch_bounds__(256) void reduce_dbl(
    const float* __restrict__ P, ushort_t* __restrict__ dtb,
    float* __restrict__ dblBC)
{
  const int f = blockIdx.x * 256 + threadIdx.x;     // < LSEQ*DXW
  float s = 0.f;
#pragma unroll
  for (int z = 0; z < KSPLIT; ++z) s += P[(size_t)z * LSEQ * DXW + f];
  const int l = f / DXW;
  const int c = f - l * DXW;
  if (c < DRNK) dtb[(size_t)l * DRNK + c] = f2b(s);
  else          dblBC[(size_t)l * 32 + (c - DRNK)] = s;
}

// ---------------------------------------------------------------------------
// Fused cast of all 5 constant inputs to bf16 (one launch) + flag zeroing.
// ---------------------------------------------------------------------------
#define CSZ0 (LSEQ * DM)        // x       4194304
#define CSZ1 (2 * DI * DM)      // W_in    4194304
#define CSZ2 (DM * DI)          // W_out   2097152
#define CSZ3 (DXW * DI)         // W_x      196608
#define CSZ4 (DI * DRNK)        // W_dt     131072
#define CTOT (CSZ0 + CSZ1 + CSZ2 + CSZ3 + CSZ4)

__global__ __launch_bounds__(256) void cast_all(
    const float* __restrict__ x, const float* __restrict__ W_in,
    const float* __restrict__ W_out, const float* __restrict__ W_x,
    const float* __restrict__ W_dt,
    ushort_t* __restrict__ xb, ushort_t* __restrict__ W_inb,
    ushort_t* __restrict__ W_outb, ushort_t* __restrict__ W_xb,
    ushort_t* __restrict__ W_dtb, int* __restrict__ flags)
{
  if (blockIdx.x == 0 && threadIdx.x < 16) flags[threadIdx.x] = 0;
  int i = (blockIdx.x * 256 + threadIdx.x) * 4;
  if (i >= CTOT) return;
  const float* src; ushort_t* dst;
  if (i < CSZ0) { src = x + i; dst = xb + i; }
  else if (i < CSZ0 + CSZ1) { int o = i - CSZ0; src = W_in + o; dst = W_inb + o; }
  else if (i < CSZ0 + CSZ1 + CSZ2) { int o = i - CSZ0 - CSZ1; src = W_out + o; dst = W_outb + o; }
  else if (i < CSZ0 + CSZ1 + CSZ2 + CSZ3) { int o = i - CSZ0 - CSZ1 - CSZ2; src = W_x + o; dst = W_xb + o; }
  else { int o = i - CSZ0 - CSZ1 - CSZ2 - CSZ3; src = W_dt + o; dst = W_dtb + o; }
  float4 v = *(const float4*)src;
  ushort4 o4;
  o4.x = f2b(v.x); o4.y = f2b(v.y); o4.z = f2b(v.z); o4.w = f2b(v.w);
  *(ushort4*)dst = o4;
}

// ---------------------------------------------------------------------------
// Sliding-window depthwise causal conv (k=4) + bias + silu, bf16 in/out.
// ---------------------------------------------------------------------------
__global__ __launch_bounds__(256) void conv2(
    const ushort_t* __restrict__ xrb, const float* __restrict__ cw,
    const float* __restrict__ cb, ushort_t* __restrict__ xsb)
{
  const int d0 = threadIdx.x * 8;
  const int l0 = blockIdx.x * 8;

  float4 w[8];
#pragma unroll
  for (int j = 0; j < 8; ++j) w[j] = *(const float4*)(cw + (size_t)(d0 + j) * DCONV);
  float cbv[8];
  *(float4*)&cbv[0] = *(const float4*)(cb + d0);
  *(float4*)&cbv[4] = *(const float4*)(cb + d0 + 4);

  float h0[8], h1[8], h2[8];
#pragma unroll
  for (int j = 0; j < 8; ++j) { h0[j] = 0.f; h1[j] = 0.f; h2[j] = 0.f; }
  if (l0 >= 3) {
    usx8 u0 = *(const usx8*)(xrb + (size_t)(l0 - 3) * (2 * DI) + d0);
    usx8 u1 = *(const usx8*)(xrb + (size_t)(l0 - 2) * (2 * DI) + d0);
    usx8 u2 = *(const usx8*)(xrb + (size_t)(l0 - 1) * (2 * DI) + d0);
#pragma unroll
    for (int j = 0; j < 8; ++j) { h0[j] = b2f(u0[j]); h1[j] = b2f(u1[j]); h2[j] = b2f(u2[j]); }
  }

#pragma unroll
  for (int i = 0; i < 8; ++i) {
    const int l = l0 + i;
    usx8 uc = *(const usx8*)(xrb + (size_t)l * (2 * DI) + d0);
    float c[8];
#pragma unroll
    for (int j = 0; j < 8; ++j) c[j] = b2f(uc[j]);
    usx8 o;
#pragma unroll
    for (int j = 0; j < 8; ++j) {
      float acc = cbv[j];
      acc = fmaf(w[j].x, h0[j], acc);
      acc = fmaf(w[j].y, h1[j], acc);
      acc = fmaf(w[j].z, h2[j], acc);
      acc = fmaf(w[j].w, c[j], acc);
      o[j] = f2b(siluf(acc));
    }
    *(usx8*)(xsb + (size_t)l * DI + d0) = o;
#pragma unroll
    for (int j = 0; j < 8; ++j) { h0[j] = h1[j]; h1[j] = h2[j]; h2[j] = c[j]; }
  }
}

// ---------------------------------------------------------------------------
// Chain detector: S4D-real init gives Av[n] = -(n+1) exactly, so
// dA[n] = q^(n+1), q = exp(-dlt): 1 exp + 16 muls instead of 16 exps.
// ---------------------------------------------------------------------------
__device__ __forceinline__ bool chain_ok(const float* Av) {
  bool ok = true;
#pragma unroll
  for (int n = 0; n < DSTATE; ++n)
    ok = ok && (fabsf(Av[n] + (float)(n + 1)) < 1e-4f);
  return ok;
}

// ---------------------------------------------------------------------------
// Fused scan, flag-based (NOT cooperative — r8's grid.sync version regressed
// 3x). Grid MUST be (8, 64) = 512 blocks @ 72KB LDS = exactly 2/CU x 256 CU
// -> all blocks co-resident by capacity => spin-wait is deadlock-free.
// Phase1: local scan -> cP,cS; release cntP[g] (agent-scope atomics handle
// cross-XCD L2 non-coherence). Blocks bid<128: chunk-carry for dn segment
// bid (waits cntP[bid>>4]==64), release cntC. Phase3: wait cntC[g]==16,
// then seeded scan + gate REUSING the LDS tiles staged in phase1.
// ---------------------------------------------------------------------------
__global__ __launch_bounds__(256) void scan_fused(
    const ushort_t* __restrict__ deltab, const ushort_t* __restrict__ xsb,
    const float* __restrict__ dblBC, const float* __restrict__ A_log,
    const float* __restrict__ Dp, const ushort_t* __restrict__ xrb,
    ushort_t* __restrict__ y1b,
    float* __restrict__ cP, float* __restrict__ cS, float* __restrict__ ch0,
    int* __restrict__ flags)
{
  int* cntP = flags;        // [8]
  int* cntC = flags + 8;    // [8]
  const int tid = threadIdx.x;
  const int g = blockIdx.x;            // dgroup (256 d's)
  const int c = blockIdx.y;            // chunk
  const int d = g * 256 + tid;
  __shared__ ushort_t Dsh[CLEN * 256];
  __shared__ ushort_t Ush[CLEN * 256];
  __shared__ float Bsh[CLEN][DSTATE];
  __shared__ float Csh[CLEN][DSTATE];

  // ---- stage tiles (coalesced 16B) ----
  const size_t rowbase = (size_t)(c * CLEN) * DI + g * 256;
  for (int i = tid; i < CLEN * 32; i += 256) {
    const int l = i >> 5;
    const int o = (i & 31) * 8;
    *(usx8*)&Dsh[l * 256 + o] = *(const usx8*)(deltab + rowbase + (size_t)l * DI + o);
    *(usx8*)&Ush[l * 256 + o] = *(const usx8*)(xsb   + rowbase + (size_t)l * DI + o);
  }
  for (int i = tid; i < CLEN * DSTATE; i += 256) {
    const int l = i >> 4, n = i & 15;
    const size_t row = (size_t)(c * CLEN + l) * 32;
    Bsh[l][n] = dblBC[row + n];
    Csh[l][n] = dblBC[row + 16 + n];
  }
  __syncthreads();

  // ---- phase 1: local scan (h=0), emit P, S ----
  float Av[DSTATE], h[DSTATE];
#pragma unroll
  for (int n = 0; n < DSTATE; ++n) {
    Av[n] = -__expf(A_log[d * DSTATE + n]);
    h[n] = 0.f;
  }
  const bool chain = chain_ok(Av);
  const size_t base = (size_t)c * DI * DSTATE + (size_t)d * DSTATE;

  if (chain) {
    float sd = 0.f;
    for (int l = 0; l < CLEN; ++l) {
      const float dlt = b2f(Dsh[l * 256 + tid]);
      const float du = dlt * b2f(Ush[l * 256 + tid]);
      sd += dlt;
      const float q = __expf(-dlt);
      float dAn = 1.f;
#pragma unroll
      for (int n = 0; n < DSTATE; ++n) {
        dAn *= q;
        h[n] = fmaf(dAn, h[n], du * Bsh[l][n]);
      }
    }
    const float Qc = __expf(-sd);
    float Pn = 1.f;
#pragma unroll
    for (int n = 0; n < DSTATE; ++n) {
      Pn *= Qc;
      cP[base + n] = Pn; cS[base + n] = h[n];
    }
  } else {
    float P[DSTATE];
#pragma unroll
    for (int n = 0; n < DSTATE; ++n) P[n] = 1.f;
    for (int l = 0; l < CLEN; ++l) {
      const float dlt = b2f(Dsh[l * 256 + tid]);
      const float du = dlt * b2f(Ush[l * 256 + tid]);
#pragma unroll
      for (int n = 0; n < DSTATE; ++n) {
        const float dA = __expf(dlt * Av[n]);
        h[n] = fmaf(dA, h[n], du * Bsh[l][n]);
        P[n] *= dA;
      }
    }
#pragma unroll
    for (int n = 0; n < DSTATE; ++n) { cP[base + n] = P[n]; cS[base + n] = h[n]; }
  }

  __syncthreads();   // all threads' cP/cS stores issued & drained (vmcnt at barrier)
  if (tid == 0)
    __hip_atomic_fetch_add(&cntP[g], 1, __ATOMIC_RELEASE, __HIP_MEMORY_SCOPE_AGENT);

  // ---- phase 2: chunk carry (blocks bid<128; segment bid covers 256 dn) ----
  const int bid = c * 8 + g;
  if (bid < (DI * DSTATE) / 256) {
    const int gs = bid >> 4;   // dgroup owning this dn segment
    if (tid == 0) {
      long spin = 0;
      while (__hip_atomic_load(&cntP[gs], __ATOMIC_ACQUIRE, __HIP_MEMORY_SCOPE_AGENT) < NCH) {
        __builtin_amdgcn_s_sleep(8);
        if (++spin > (1L << 22)) break;   // safety valve: fail visibly, don't wedge
      }
    }
    __syncthreads();
    const int dn = bid * 256 + tid;
    float hh = 0.f;
    for (int cc = 0; cc < NCH; ++cc) {
      const size_t o = (size_t)cc * DI * DSTATE + dn;
      const float p = cP[o], s = cS[o];
      ch0[o] = hh;                    // ch0 aliases cP (read-then-write, same thread)
      hh = fmaf(p, hh, s);
    }
    __syncthreads();
    if (tid == 0)
      __hip_atomic_fetch_add(&cntC[gs], 1, __ATOMIC_RELEASE, __HIP_MEMORY_SCOPE_AGENT);
  }

  // ---- phase 3: wait for own dgroup's 16 segments, then seeded scan + gate ----
  if (tid == 0) {
    long spin = 0;
    while (__hip_atomic_load(&cntC[g], __ATOMIC_ACQUIRE, __HIP_MEMORY_SCOPE_AGENT) < 16) {
      __builtin_amdgcn_s_sleep(8);
      if (++spin > (1L << 22)) break;
    }
  }
  __syncthreads();

#pragma unroll
  for (int n = 0; n < DSTATE; ++n) h[n] = ch0[base + n];
  const float Dd = Dp[d];
  const ushort_t* resp = xrb + (size_t)(c * CLEN) * (2 * DI) + DI + d;
  ushort_t* yp = y1b + (size_t)(c * CLEN) * DI + d;

  if (chain) {
    for (int l = 0; l < CLEN; ++l) {
      const float dlt = b2f(Dsh[l * 256 + tid]);
      const float u = b2f(Ush[l * 256 + tid]);
      const float du = dlt * u;
      const float q = __expf(-dlt);
      float dAn = 1.f;
      float y = 0.f;
#pragma unroll
      for (int n = 0; n < DSTATE; ++n) {
        dAn *= q;
        h[n] = fmaf(dAn, h[n], du * Bsh[l][n]);
        y = fmaf(h[n], Csh[l][n], y);
      }
      y = fmaf(u, Dd, y);
      const float res = b2f(resp[(size_t)l * (2 * DI)]);
      yp[(size_t)l * DI] = f2b(y * siluf(res));
    }
  } else {
    for (int l = 0; l < CLEN; ++l) {
      const float dlt = b2f(Dsh[l * 256 + tid]);
      const float u = b2f(Ush[l * 256 + tid]);
      const float du = dlt * u;
      float y = 0.f;
#pragma unroll
      for (int n = 0; n < DSTATE; ++n) {
        const float dA = __expf(dlt * Av[n]);
        h[n] = fmaf(dA, h[n], du * Bsh[l][n]);
        y = fmaf(h[n], Csh[l][n], y);
      }
      y = fmaf(u, Dd, y);
      const float res = b2f(resp[(size_t)l * (2 * DI)]);
      yp[(size_t)l * DI] = f2b(y * siluf(res));
    }
  }
}

// ---------------------------------------------------------------------------
extern "C" void kernel_launch(void* const* d_in, const int* in_sizes, int n_in,
                              void* d_out, int out_size, void* d_ws, size_t ws_size,
                              hipStream_t stream) {
  (void)in_sizes; (void)n_in; (void)out_size; (void)ws_size;
  const float* x      = (const float*)d_in[0];
  const float* W_in   = (const float*)d_in[1];
  const float* conv_w = (const float*)d_in[2];
  const float* conv_b = (const float*)d_in[3];
  const float* W_x    = (const float*)d_in[4];
  const float* W_dt   = (const float*)d_in[5];
  const float* b_dt   = (const float*)d_in[6];
  const float* A_log  = (const float*)d_in[7];
  const float* Dp     = (const float*)d_in[8];
  const float* W_out  = (const float*)d_in[9];
  float* out = (float*)d_out;

  // workspace layout.
  // partial (KSPLIT*L*96 f = 12.6 MB) aliases [cP, cS]:
  //   timeline: gemm_dbl writes partial -> reduce_dbl consumes it ->
  //   delta-GEMM -> scan_fused writes cP/cS. No live overlap.
  float* ws    = (float*)d_ws;
  float* cP    = ws;                                   // 2.1M f
  float* cS    = cP + (size_t)NCH * DI * DSTATE;       // 2.1M f
  ushort_t* deltab = (ushort_t*)(cS + (size_t)NCH * DI * DSTATE);  // L*DI bf16
  ushort_t* xrb   = deltab + (size_t)LSEQ * DI;        // L*2DI
  ushort_t* xsb   = xrb   + (size_t)LSEQ * 2 * DI;     // L*DI
  ushort_t* y1b   = xsb   + (size_t)LSEQ * DI;         // L*DI
  ushort_t* xb    = y1b   + (size_t)LSEQ * DI;         // L*DM
  ushort_t* W_inb = xb    + (size_t)LSEQ * DM;         // 2DI*DM
  ushort_t* W_outb= W_inb + (size_t)2 * DI * DM;       // DM*DI
  ushort_t* W_xb  = W_outb+ (size_t)DM * DI;           // 96*DI
  ushort_t* W_dtb = W_xb  + (size_t)DXW * DI;          // DI*64
  ushort_t* dtb   = W_dtb + (size_t)DI * DRNK;         // L*64
  float* dblBC = (float*)(dtb + (size_t)LSEQ * DRNK);  // L*32 f
  int* flags = (int*)(dblBC + (size_t)LSEQ * 32);      // 16 ints
  float* partial = cP;   // alias (see above)
  float* ch0 = cP;       // alias (in-place in carry)

  // 0) all input casts in one launch (+ flag zeroing)
  hipLaunchKernelGGL(cast_all, dim3((CTOT / 4 + 255) / 256), dim3(256), 0, stream,
                     x, W_in, W_out, W_x, W_dt, xb, W_inb, W_outb, W_xb, W_dtb,
                     flags);

  // 1) xrb = bf16(x @ W_in.T)  (M=4096, N=4096, K=1024), 128x128 tile
  hipLaunchKernelGGL(HIP_KERNEL_NAME(gemm_bf16<1, 128>),
                     dim3((2 * DI) / 128, LSEQ / 128), dim3(256), 0, stream,
                     xb, DM, W_inb, DM, (void*)xrb, 2 * DI, DM, nullptr);

  // 2) xsb = bf16(silu(conv(xi) + b)) — sliding window
  hipLaunchKernelGGL(conv2, dim3(LSEQ / 8), dim3(256), 0, stream,
                     xrb, conv_w, conv_b, xsb);

  // 3) partial[z] = xsb @ W_xb.T chunk z; then reduce -> dtb bf16 + dblBC f32
  hipLaunchKernelGGL(gemm_dbl, dim3(1, LSEQ / 128, KSPLIT), dim3(256), 0, stream,
                     xsb, W_xb, partial);
  hipLaunchKernelGGL(reduce_dbl, dim3((LSEQ * DXW) / 256), dim3(256), 0, stream,
                     partial, dtb, dblBC);

  // 4) deltab = bf16(softplus(dtb @ W_dtb.T + b_dt))  (K=64)
  hipLaunchKernelGGL(HIP_KERNEL_NAME(gemm_bf16<2, 128>),
                     dim3(DI / 128, LSEQ / 128), dim3(256), 0, stream,
                     dtb, DRNK, W_dtb, DRNK, (void*)deltab, DI, DRNK, b_dt);

  // 5) fused flag-synced scan (512 blocks, all co-resident: 72KB LDS -> 2/CU)
  hipLaunchKernelGGL(scan_fused, dim3(DI / 256, NCH), dim3(256), 0, stream,
                     deltab, xsb, dblBC, A_log, Dp, xrb, y1b, cP, cS, ch0,
                     flags);

  // 6) out = y1b @ W_out.T  (M=4096, N=1024, K=2048), 128x64 tile -> 512 blocks
  hipLaunchKernelGGL(HIP_KERNEL_NAME(gemm_bf16<0, 64>),
                     dim3(DM / 64, LSEQ / 128), dim3(256), 0, stream,
                     y1b, DI, W_outb, DI, (void*)out, DM, DI, nullptr);
}

// Round 11
// 315.509 us; speedup vs baseline: 1.3233x; 1.3233x over previous
//
#include <hip/hip_runtime.h>
#include <cstdint>
#include <cstddef>

// Problem constants
#define LSEQ 4096
#define DM 1024
#define DI 2048
#define DCONV 4
#define DRNK 64
#define DSTATE 16
#define DXW 96        // DRNK + 2*DSTATE
#define NCH 128       // scan chunks (r11: 64->128 for scan occupancy)
#define CLEN 32       // LSEQ / NCH
#define KSPLIT 16     // split-K for dbl GEMM (r11: back to 16 -> 512 blocks, 2/CU)

typedef unsigned short ushort_t;
typedef __bf16 bfx8 __attribute__((ext_vector_type(8)));
typedef float  fx4  __attribute__((ext_vector_type(4)));
typedef ushort_t usx8 __attribute__((ext_vector_type(8)));

__device__ __forceinline__ float siluf(float x) { return x / (1.f + __expf(-x)); }
__device__ __forceinline__ float softplusf(float x) {
  return fmaxf(x, 0.f) + log1pf(__expf(-fabsf(x)));
}
__device__ __forceinline__ ushort_t f2b(float x) {
  __bf16 b = (__bf16)x;   // RNE
  return __builtin_bit_cast(ushort_t, b);
}
__device__ __forceinline__ float b2f(ushort_t u) {
  unsigned int x = ((unsigned int)u) << 16;
  return __builtin_bit_cast(float, x);
}
__device__ __forceinline__ void async16(const void* g, void* l) {
  __builtin_amdgcn_global_load_lds(
      (const __attribute__((address_space(1))) unsigned int*)g,
      (__attribute__((address_space(3))) unsigned int*)l, 16, 0, 0);
}

// ---------------------------------------------------------------------------
// bf16 MFMA NT GEMM: 128xBN tile (BN=128 or 64), BK=32, 4 waves 2x2.
// XOR-swizzled LDS (conflict-free, r5: SQ_LDS_BANK_CONFLICT=0).
// EPI: 0 = f32 store, 1 = bf16 store, 2 = bf16 store of softplus(acc+bias[n]).
// NOTE (r6): 128x256 tile regressed (occupancy 10%, 89us vs 60us).
// NOTE (r8/r10): scan fusion (cooperative OR flag-synced) regressed ~3x.
//   The 3-pass scan + this GEMM structure is the validated plateau.
// ---------------------------------------------------------------------------
template <int EPI, int BN>
__global__ __launch_bounds__(256) void gemm_bf16(
    const ushort_t* __restrict__ A, int lda,
    const ushort_t* __restrict__ B, int ldb,
    void* __restrict__ Cv, int ldc, int K,
    const float* __restrict__ bias)
{
  constexpr int NJ = BN / 32;
  __shared__ ushort_t As[128 * 32];
  __shared__ ushort_t Bs[BN * 32];
  const int tid  = threadIdx.x;
  const int m0   = blockIdx.y * 128, n0 = blockIdx.x * BN;
  const int lane = tid & 63;
  const int wave = tid >> 6;
  const int wm   = (wave >> 1) * 64, wn = (wave & 1) * (BN / 2);
  const int lm   = lane & 15;
  const int r0 = tid >> 2;
  const int cswz = (((tid & 3) ^ ((r0 >> 1) & 3))) * 8;
  const int swz = (((lane >> 4) ^ ((lm >> 1) & 3))) * 8;

  fx4 acc[4][NJ] = {};

  const ushort_t* ga = A + (size_t)(m0 + r0) * lda + cswz;
  const ushort_t* gb = B + (size_t)(n0 + r0) * ldb + cswz;
  ushort_t* la0 = &As[r0 * 32 + (tid & 3) * 8];
  ushort_t* la1 = &As[(r0 + 64) * 32 + (tid & 3) * 8];
  ushort_t* lb0 = &Bs[r0 * 32 + (tid & 3) * 8];
  ushort_t* lb1 = (BN == 128) ? &Bs[(r0 + 64) * 32 + (tid & 3) * 8] : nullptr;

  for (int k0 = 0; k0 < K; k0 += 32) {
    async16(ga + k0, la0);
    async16(ga + (size_t)64 * lda + k0, la1);
    async16(gb + k0, lb0);
    if (BN == 128) async16(gb + (size_t)64 * ldb + k0, lb1);
    __syncthreads();

    bfx8 af[4], bfr[NJ];
#pragma unroll
    for (int i = 0; i < 4; ++i)
      af[i] = *(const bfx8*)&As[(wm + i * 16 + lm) * 32 + swz];
#pragma unroll
    for (int j = 0; j < NJ; ++j)
      bfr[j] = *(const bfx8*)&Bs[(wn + j * 16 + lm) * 32 + swz];
#pragma unroll
    for (int i = 0; i < 4; ++i)
#pragma unroll
      for (int j = 0; j < NJ; ++j)
        acc[i][j] = __builtin_amdgcn_mfma_f32_16x16x32_bf16(af[i], bfr[j], acc[i][j], 0, 0, 0);
    __syncthreads();
  }

  // C/D layout (16x16): col = lane&15, row = (lane>>4)*4 + reg
  const int crow = (lane >> 4) * 4;
  const int ccol = lane & 15;
#pragma unroll
  for (int i = 0; i < 4; ++i)
#pragma unroll
    for (int r = 0; r < 4; ++r) {
      const size_t rowoff = (size_t)(m0 + wm + i * 16 + crow + r) * ldc + n0 + wn + ccol;
      if (EPI == 1) {
        ushort_t* cp = (ushort_t*)Cv + rowoff;
#pragma unroll
        for (int j = 0; j < NJ; ++j) cp[j * 16] = f2b(acc[i][j][r]);
      } else if (EPI == 2) {
        ushort_t* cp = (ushort_t*)Cv + rowoff;
        const int nb = n0 + wn + ccol;
#pragma unroll
        for (int j = 0; j < NJ; ++j)
          cp[j * 16] = f2b(softplusf(acc[i][j][r] + bias[nb + j * 16]));
      } else {
        float* cp = (float*)Cv + rowoff;
#pragma unroll
        for (int j = 0; j < NJ; ++j) cp[j * 16] = acc[i][j][r];
      }
    }
}

// ---------------------------------------------------------------------------
// dbl GEMM: partial[z][L,96] f32 = xsb[L,2048]bf16 @ W_xb[96,2048]bf16^T
// over K-chunk z (KSPLIT=16 -> 128-wide chunks, 512 blocks = 2/CU).
// Plain stores (no atomics).
// ---------------------------------------------------------------------------
__global__ __launch_bounds__(256) void gemm_dbl(
    const ushort_t* __restrict__ A, const ushort_t* __restrict__ B,
    float* __restrict__ P)
{
  __shared__ ushort_t As[128 * 32];
  __shared__ ushort_t Bs[128 * 32];
  const int tid  = threadIdx.x;
  const int m0   = blockIdx.y * 128;
  const int lane = tid & 63;
  const int wave = tid >> 6;
  const int wm   = (wave >> 1) * 64, wn = (wave & 1) * 48;
  const int lm   = lane & 15;
  const int r0 = tid >> 2;
  const int cswz = (((tid & 3) ^ ((r0 >> 1) & 3))) * 8;
  const int swz  = (((lane >> 4) ^ ((lm >> 1) & 3))) * 8;
  const int kbeg = blockIdx.z * (DI / KSPLIT);

  fx4 acc[4][3] = {};

  const int brow1 = (r0 + 64 < DXW) ? r0 + 64 : DXW - 1;  // clamp; rows>=96 unused
  const ushort_t* ga  = A + (size_t)(m0 + r0) * DI + kbeg + cswz;
  const ushort_t* gb0 = B + (size_t)r0 * DI + kbeg + cswz;
  const ushort_t* gb1 = B + (size_t)brow1 * DI + kbeg + cswz;
  ushort_t* la0 = &As[r0 * 32 + (tid & 3) * 8];
  ushort_t* la1 = &As[(r0 + 64) * 32 + (tid & 3) * 8];
  ushort_t* lb0 = &Bs[r0 * 32 + (tid & 3) * 8];
  ushort_t* lb1 = &Bs[(r0 + 64) * 32 + (tid & 3) * 8];

  for (int k0 = 0; k0 < DI / KSPLIT; k0 += 32) {
    async16(ga + k0, la0);
    async16(ga + (size_t)64 * DI + k0, la1);
    async16(gb0 + k0, lb0);
    async16(gb1 + k0, lb1);
    __syncthreads();

    bfx8 af[4], bfr[3];
#pragma unroll
    for (int i = 0; i < 4; ++i)
      af[i] = *(const bfx8*)&As[(wm + i * 16 + lm) * 32 + swz];
#pragma unroll
    for (int j = 0; j < 3; ++j)
      bfr[j] = *(const bfx8*)&Bs[(wn + j * 16 + lm) * 32 + swz];
#pragma unroll
    for (int i = 0; i < 4; ++i)
#pragma unroll
      for (int j = 0; j < 3; ++j)
        acc[i][j] = __builtin_amdgcn_mfma_f32_16x16x32_bf16(af[i], bfr[j], acc[i][j], 0, 0, 0);
    __syncthreads();
  }

  float* base = P + (size_t)blockIdx.z * LSEQ * DXW;
  const int crow = (lane >> 4) * 4;
  const int ccol = lane & 15;
#pragma unroll
  for (int i = 0; i < 4; ++i)
#pragma unroll
    for (int r = 0; r < 4; ++r) {
      float* cp = base + (size_t)(m0 + wm + i * 16 + crow + r) * DXW + wn + ccol;
#pragma unroll
      for (int j = 0; j < 3; ++j)
        cp[j * 16] = acc[i][j][r];
    }
}

// ---------------------------------------------------------------------------
// reduce_dbl: sum KSPLIT partials; emit dtb = bf16(cols 0..63) and
// dblBC = f32 compact (cols 64..95 -> [l][32]). Deterministic z-order.
// ---------------------------------------------------------------------------
__global__ __launch_bounds__(256) void reduce_dbl(
    const float* __restrict__ P, ushort_t* __restrict__ dtb,
    float* __restrict__ dblBC)
{
  const int f = blockIdx.x * 256 + threadIdx.x;     // < LSEQ*DXW
  float s = 0.f;
#pragma unroll
  for (int z = 0; z < KSPLIT; ++z) s += P[(size_t)z * LSEQ * DXW + f];
  const int l = f / DXW;
  const int c = f - l * DXW;
  if (c < DRNK) dtb[(size_t)l * DRNK + c] = f2b(s);
  else          dblBC[(size_t)l * 32 + (c - DRNK)] = s;
}

// ---------------------------------------------------------------------------
// Fused cast of all 5 constant inputs to bf16 (one launch).
// ---------------------------------------------------------------------------
#define CSZ0 (LSEQ * DM)        // x       4194304
#define CSZ1 (2 * DI * DM)      // W_in    4194304
#define CSZ2 (DM * DI)          // W_out   2097152
#define CSZ3 (DXW * DI)         // W_x      196608
#define CSZ4 (DI * DRNK)        // W_dt     131072
#define CTOT (CSZ0 + CSZ1 + CSZ2 + CSZ3 + CSZ4)

__global__ __launch_bounds__(256) void cast_all(
    const float* __restrict__ x, const float* __restrict__ W_in,
    const float* __restrict__ W_out, const float* __restrict__ W_x,
    const float* __restrict__ W_dt,
    ushort_t* __restrict__ xb, ushort_t* __restrict__ W_inb,
    ushort_t* __restrict__ W_outb, ushort_t* __restrict__ W_xb,
    ushort_t* __restrict__ W_dtb)
{
  int i = (blockIdx.x * 256 + threadIdx.x) * 4;
  if (i >= CTOT) return;
  const float* src; ushort_t* dst;
  if (i < CSZ0) { src = x + i; dst = xb + i; }
  else if (i < CSZ0 + CSZ1) { int o = i - CSZ0; src = W_in + o; dst = W_inb + o; }
  else if (i < CSZ0 + CSZ1 + CSZ2) { int o = i - CSZ0 - CSZ1; src = W_out + o; dst = W_outb + o; }
  else if (i < CSZ0 + CSZ1 + CSZ2 + CSZ3) { int o = i - CSZ0 - CSZ1 - CSZ2; src = W_x + o; dst = W_xb + o; }
  else { int o = i - CSZ0 - CSZ1 - CSZ2 - CSZ3; src = W_dt + o; dst = W_dtb + o; }
  float4 v = *(const float4*)src;
  ushort4 o4;
  o4.x = f2b(v.x); o4.y = f2b(v.y); o4.z = f2b(v.z); o4.w = f2b(v.w);
  *(ushort4*)dst = o4;
}

// ---------------------------------------------------------------------------
// Sliding-window depthwise causal conv (k=4) + bias + silu, bf16 in/out.
// ---------------------------------------------------------------------------
__global__ __launch_bounds__(256) void conv2(
    const ushort_t* __restrict__ xrb, const float* __restrict__ cw,
    const float* __restrict__ cb, ushort_t* __restrict__ xsb)
{
  const int d0 = threadIdx.x * 8;
  const int l0 = blockIdx.x * 8;

  float4 w[8];
#pragma unroll
  for (int j = 0; j < 8; ++j) w[j] = *(const float4*)(cw + (size_t)(d0 + j) * DCONV);
  float cbv[8];
  *(float4*)&cbv[0] = *(const float4*)(cb + d0);
  *(float4*)&cbv[4] = *(const float4*)(cb + d0 + 4);

  float h0[8], h1[8], h2[8];
#pragma unroll
  for (int j = 0; j < 8; ++j) { h0[j] = 0.f; h1[j] = 0.f; h2[j] = 0.f; }
  if (l0 >= 3) {
    usx8 u0 = *(const usx8*)(xrb + (size_t)(l0 - 3) * (2 * DI) + d0);
    usx8 u1 = *(const usx8*)(xrb + (size_t)(l0 - 2) * (2 * DI) + d0);
    usx8 u2 = *(const usx8*)(xrb + (size_t)(l0 - 1) * (2 * DI) + d0);
#pragma unroll
    for (int j = 0; j < 8; ++j) { h0[j] = b2f(u0[j]); h1[j] = b2f(u1[j]); h2[j] = b2f(u2[j]); }
  }

#pragma unroll
  for (int i = 0; i < 8; ++i) {
    const int l = l0 + i;
    usx8 uc = *(const usx8*)(xrb + (size_t)l * (2 * DI) + d0);
    float c[8];
#pragma unroll
    for (int j = 0; j < 8; ++j) c[j] = b2f(uc[j]);
    usx8 o;
#pragma unroll
    for (int j = 0; j < 8; ++j) {
      float acc = cbv[j];
      acc = fmaf(w[j].x, h0[j], acc);
      acc = fmaf(w[j].y, h1[j], acc);
      acc = fmaf(w[j].z, h2[j], acc);
      acc = fmaf(w[j].w, c[j], acc);
      o[j] = f2b(siluf(acc));
    }
    *(usx8*)(xsb + (size_t)l * DI + d0) = o;
#pragma unroll
    for (int j = 0; j < 8; ++j) { h0[j] = h1[j]; h1[j] = h2[j]; h2[j] = c[j]; }
  }
}

// ---------------------------------------------------------------------------
// Chain detector: S4D-real init gives Av[n] = -(n+1) exactly, so
// dA[n] = q^(n+1), q = exp(-dlt): 1 exp + 16 muls instead of 16 exps.
// ---------------------------------------------------------------------------
__device__ __forceinline__ bool chain_ok(const float* Av) {
  bool ok = true;
#pragma unroll
  for (int n = 0; n < DSTATE; ++n)
    ok = ok && (fabsf(Av[n] + (float)(n + 1)) < 1e-4f);
  return ok;
}

// ---------------------------------------------------------------------------
// Scan pass 1 (LDS-staged): local scan (h=0), emit P=prod(dA), S=end state.
// r11: CLEN=32 -> LDS 34 KB -> 4 blocks/CU (16 waves) vs 2 at CLEN=64.
// Chain path: P[n] = exp(-sum dlt)^(n+1) — one exp per chunk.
// ---------------------------------------------------------------------------
__global__ __launch_bounds__(256) void scan_pass1(
    const ushort_t* __restrict__ deltab, const ushort_t* __restrict__ xsb,
    const float* __restrict__ dblBC, const float* __restrict__ A_log,
    float* __restrict__ cP, float* __restrict__ cS)
{
  const int tid = threadIdx.x;
  const int g = blockIdx.x;            // dgroup (256 d's)
  const int c = blockIdx.y;            // chunk
  const int d = g * 256 + tid;
  __shared__ ushort_t Dsh[CLEN * 256];
  __shared__ ushort_t Ush[CLEN * 256];
  __shared__ float Bsh[CLEN][DSTATE];

  const size_t rowbase = (size_t)(c * CLEN) * DI + g * 256;
  for (int i = tid; i < CLEN * 32; i += 256) {
    const int l = i >> 5;
    const int o = (i & 31) * 8;
    *(usx8*)&Dsh[l * 256 + o] = *(const usx8*)(deltab + rowbase + (size_t)l * DI + o);
    *(usx8*)&Ush[l * 256 + o] = *(const usx8*)(xsb   + rowbase + (size_t)l * DI + o);
  }
  for (int i = tid; i < CLEN * DSTATE; i += 256) {
    const int l = i >> 4, n = i & 15;
    Bsh[l][n] = dblBC[(size_t)(c * CLEN + l) * 32 + n];
  }
  __syncthreads();

  float Av[DSTATE], h[DSTATE];
#pragma unroll
  for (int n = 0; n < DSTATE; ++n) {
    Av[n] = -__expf(A_log[d * DSTATE + n]);
    h[n] = 0.f;
  }
  const size_t base = (size_t)c * DI * DSTATE + (size_t)d * DSTATE;

  if (chain_ok(Av)) {
    float sd = 0.f;
    for (int l = 0; l < CLEN; ++l) {
      const float dlt = b2f(Dsh[l * 256 + tid]);
      const float du = dlt * b2f(Ush[l * 256 + tid]);
      sd += dlt;
      const float q = __expf(-dlt);
      float dAn = 1.f;
#pragma unroll
      for (int n = 0; n < DSTATE; ++n) {
        dAn *= q;
        h[n] = fmaf(dAn, h[n], du * Bsh[l][n]);
      }
    }
    const float Qc = __expf(-sd);
    float Pn = 1.f;
#pragma unroll
    for (int n = 0; n < DSTATE; ++n) {
      Pn *= Qc;
      cP[base + n] = Pn; cS[base + n] = h[n];
    }
  } else {
    float P[DSTATE];
#pragma unroll
    for (int n = 0; n < DSTATE; ++n) P[n] = 1.f;
    for (int l = 0; l < CLEN; ++l) {
      const float dlt = b2f(Dsh[l * 256 + tid]);
      const float du = dlt * b2f(Ush[l * 256 + tid]);
#pragma unroll
      for (int n = 0; n < DSTATE; ++n) {
        const float dA = __expf(dlt * Av[n]);
        h[n] = fmaf(dA, h[n], du * Bsh[l][n]);
        P[n] *= dA;
      }
    }
#pragma unroll
    for (int n = 0; n < DSTATE; ++n) { cP[base + n] = P[n]; cS[base + n] = h[n]; }
  }
}

// ---------------------------------------------------------------------------
// Scan pass 2: sequential carry over chunks; ch0 may alias cP.
// ---------------------------------------------------------------------------
__global__ __launch_bounds__(256) void scan_pass2(
    const float* __restrict__ cP, const float* __restrict__ cS,
    float* __restrict__ ch0)
{
  const int dn = blockIdx.x * 256 + threadIdx.x;
  float h = 0.f;
  for (int c = 0; c < NCH; ++c) {
    const size_t o = (size_t)c * DI * DSTATE + dn;
    const float p = cP[o], s = cS[o];
    ch0[o] = h;
    h = fmaf(p, h, s);
  }
}

// ---------------------------------------------------------------------------
// Scan pass 3 (LDS-staged) + gate: y1b = bf16( (scan_y + u*D) * silu(res) ).
// r11: CLEN=32 -> LDS 36 KB -> 4 blocks/CU. Chain path for dA.
// ---------------------------------------------------------------------------
__global__ __launch_bounds__(256) void scan_pass3(
    const ushort_t* __restrict__ deltab, const ushort_t* __restrict__ xsb,
    const float* __restrict__ dblBC, const float* __restrict__ A_log,
    const float* __restrict__ ch0, const float* __restrict__ Dp,
    const ushort_t* __restrict__ xrb, ushort_t* __restrict__ y1b)
{
  const int tid = threadIdx.x;
  const int g = blockIdx.x;
  const int c = blockIdx.y;
  const int d = g * 256 + tid;
  __shared__ ushort_t Dsh[CLEN * 256];
  __shared__ ushort_t Ush[CLEN * 256];
  __shared__ float Bsh[CLEN][DSTATE];
  __shared__ float Csh[CLEN][DSTATE];

  const size_t rowbase = (size_t)(c * CLEN) * DI + g * 256;
  for (int i = tid; i < CLEN * 32; i += 256) {
    const int l = i >> 5;
    const int o = (i & 31) * 8;
    *(usx8*)&Dsh[l * 256 + o] = *(const usx8*)(deltab + rowbase + (size_t)l * DI + o);
    *(usx8*)&Ush[l * 256 + o] = *(const usx8*)(xsb   + rowbase + (size_t)l * DI + o);
  }
  for (int i = tid; i < CLEN * DSTATE; i += 256) {
    const int l = i >> 4, n = i & 15;
    const size_t row = (size_t)(c * CLEN + l) * 32;
    Bsh[l][n] = dblBC[row + n];
    Csh[l][n] = dblBC[row + 16 + n];
  }
  __syncthreads();

  float Av[DSTATE], h[DSTATE];
  const size_t base = (size_t)c * DI * DSTATE + (size_t)d * DSTATE;
#pragma unroll
  for (int n = 0; n < DSTATE; ++n) {
    Av[n] = -__expf(A_log[d * DSTATE + n]);
    h[n] = ch0[base + n];
  }
  const float Dd = Dp[d];
  const ushort_t* resp = xrb + (size_t)(c * CLEN) * (2 * DI) + DI + d;
  ushort_t* yp = y1b + (size_t)(c * CLEN) * DI + d;

  if (chain_ok(Av)) {
    for (int l = 0; l < CLEN; ++l) {
      const float dlt = b2f(Dsh[l * 256 + tid]);
      const float u = b2f(Ush[l * 256 + tid]);
      const float du = dlt * u;
      const float q = __expf(-dlt);
      float dAn = 1.f;
      float y = 0.f;
#pragma unroll
      for (int n = 0; n < DSTATE; ++n) {
        dAn *= q;
        h[n] = fmaf(dAn, h[n], du * Bsh[l][n]);
        y = fmaf(h[n], Csh[l][n], y);
      }
      y = fmaf(u, Dd, y);
      const float res = b2f(resp[(size_t)l * (2 * DI)]);
      yp[(size_t)l * DI] = f2b(y * siluf(res));
    }
  } else {
    for (int l = 0; l < CLEN; ++l) {
      const float dlt = b2f(Dsh[l * 256 + tid]);
      const float u = b2f(Ush[l * 256 + tid]);
      const float du = dlt * u;
      float y = 0.f;
#pragma unroll
      for (int n = 0; n < DSTATE; ++n) {
        const float dA = __expf(dlt * Av[n]);
        h[n] = fmaf(dA, h[n], du * Bsh[l][n]);
        y = fmaf(h[n], Csh[l][n], y);
      }
      y = fmaf(u, Dd, y);
      const float res = b2f(resp[(size_t)l * (2 * DI)]);
      yp[(size_t)l * DI] = f2b(y * siluf(res));
    }
  }
}

// ---------------------------------------------------------------------------
extern "C" void kernel_launch(void* const* d_in, const int* in_sizes, int n_in,
                              void* d_out, int out_size, void* d_ws, size_t ws_size,
                              hipStream_t stream) {
  (void)in_sizes; (void)n_in; (void)out_size; (void)ws_size;
  const float* x      = (const float*)d_in[0];
  const float* W_in   = (const float*)d_in[1];
  const float* conv_w = (const float*)d_in[2];
  const float* conv_b = (const float*)d_in[3];
  const float* W_x    = (const float*)d_in[4];
  const float* W_dt   = (const float*)d_in[5];
  const float* b_dt   = (const float*)d_in[6];
  const float* A_log  = (const float*)d_in[7];
  const float* Dp     = (const float*)d_in[8];
  const float* W_out  = (const float*)d_in[9];
  float* out = (float*)d_out;

  // workspace layout.
  // partial (KSPLIT*L*96 f = 25.2 MB) aliases [cP, cS] (33.5 MB):
  //   timeline: gemm_dbl writes partial -> reduce_dbl consumes it ->
  //   delta-GEMM -> scan_pass1 writes cP/cS. No live overlap.
  float* ws    = (float*)d_ws;
  float* cP    = ws;                                   // NCH*DI*DSTATE f = 16.8 MB
  float* cS    = cP + (size_t)NCH * DI * DSTATE;       // 16.8 MB
  ushort_t* deltab = (ushort_t*)(cS + (size_t)NCH * DI * DSTATE);  // L*DI bf16
  ushort_t* xrb   = deltab + (size_t)LSEQ * DI;        // L*2DI
  ushort_t* xsb   = xrb   + (size_t)LSEQ * 2 * DI;     // L*DI
  ushort_t* y1b   = xsb   + (size_t)LSEQ * DI;         // L*DI
  ushort_t* xb    = y1b   + (size_t)LSEQ * DI;         // L*DM
  ushort_t* W_inb = xb    + (size_t)LSEQ * DM;         // 2DI*DM
  ushort_t* W_outb= W_inb + (size_t)2 * DI * DM;       // DM*DI
  ushort_t* W_xb  = W_outb+ (size_t)DM * DI;           // 96*DI
  ushort_t* W_dtb = W_xb  + (size_t)DXW * DI;          // DI*64
  ushort_t* dtb   = W_dtb + (size_t)DI * DRNK;         // L*64
  float* dblBC = (float*)(dtb + (size_t)LSEQ * DRNK);  // L*32 f
  float* partial = cP;   // alias (see above)
  float* ch0 = cP;       // alias (in-place in scan_pass2)

  // 0) all input casts in one launch
  hipLaunchKernelGGL(cast_all, dim3((CTOT / 4 + 255) / 256), dim3(256), 0, stream,
                     x, W_in, W_out, W_x, W_dt, xb, W_inb, W_outb, W_xb, W_dtb);

  // 1) xrb = bf16(x @ W_in.T)  (M=4096, N=4096, K=1024), 128x128 tile
  hipLaunchKernelGGL(HIP_KERNEL_NAME(gemm_bf16<1, 128>),
                     dim3((2 * DI) / 128, LSEQ / 128), dim3(256), 0, stream,
                     xb, DM, W_inb, DM, (void*)xrb, 2 * DI, DM, nullptr);

  // 2) xsb = bf16(silu(conv(xi) + b)) — sliding window
  hipLaunchKernelGGL(conv2, dim3(LSEQ / 8), dim3(256), 0, stream,
                     xrb, conv_w, conv_b, xsb);

  // 3) partial[z] = xsb @ W_xb.T chunk z; then reduce -> dtb bf16 + dblBC f32
  hipLaunchKernelGGL(gemm_dbl, dim3(1, LSEQ / 128, KSPLIT), dim3(256), 0, stream,
                     xsb, W_xb, partial);
  hipLaunchKernelGGL(reduce_dbl, dim3((LSEQ * DXW) / 256), dim3(256), 0, stream,
                     partial, dtb, dblBC);

  // 4) deltab = bf16(softplus(dtb @ W_dtb.T + b_dt))  (K=64)
  hipLaunchKernelGGL(HIP_KERNEL_NAME(gemm_bf16<2, 128>),
                     dim3(DI / 128, LSEQ / 128), dim3(256), 0, stream,
                     dtb, DRNK, W_dtb, DRNK, (void*)deltab, DI, DRNK, b_dt);

  // 5) chunked selective scan (3-pass; CLEN=32 for 4 blocks/CU occupancy)
  hipLaunchKernelGGL(scan_pass1, dim3(DI / 256, NCH), dim3(256), 0, stream,
                     deltab, xsb, dblBC, A_log, cP, cS);
  hipLaunchKernelGGL(scan_pass2, dim3((DI * DSTATE) / 256), dim3(256), 0, stream,
                     cP, cS, ch0);
  hipLaunchKernelGGL(scan_pass3, dim3(DI / 256, NCH), dim3(256), 0, stream,
                     deltab, xsb, dblBC, A_log, ch0, Dp, xrb, y1b);

  // 6) out = y1b @ W_out.T  (M=4096, N=1024, K=2048), 128x64 tile -> 512 blocks
  hipLaunchKernelGGL(HIP_KERNEL_NAME(gemm_bf16<0, 64>),
                     dim3(DM / 64, LSEQ / 128), dim3(256), 0, stream,
                     y1b, DI, W_outb, DI, (void*)out, DM, DI, nullptr);
}

// Round 12
// 302.555 us; speedup vs baseline: 1.3799x; 1.0428x over previous
//
#include <hip/hip_runtime.h>
#include <cstdint>
#include <cstddef>

// Problem constants
#define LSEQ 4096
#define DM 1024
#define DI 2048
#define DCONV 4
#define DRNK 64
#define DSTATE 16
#define DXW 96        // DRNK + 2*DSTATE
#define NCH 64        // r11: CLEN=32/NCH=128 regressed (315 vs 309) — keep 64
#define CLEN 64       // LSEQ / NCH
#define KSPLIT 8      // split-K for dbl GEMM (r9 config)

typedef unsigned short ushort_t;
typedef __bf16 bfx8 __attribute__((ext_vector_type(8)));
typedef float  fx4  __attribute__((ext_vector_type(4)));
typedef float  fx16 __attribute__((ext_vector_type(16)));
typedef ushort_t usx8 __attribute__((ext_vector_type(8)));

__device__ __forceinline__ float siluf(float x) { return x / (1.f + __expf(-x)); }
__device__ __forceinline__ float softplusf(float x) {
  return fmaxf(x, 0.f) + log1pf(__expf(-fabsf(x)));
}
__device__ __forceinline__ ushort_t f2b(float x) {
  __bf16 b = (__bf16)x;   // RNE
  return __builtin_bit_cast(ushort_t, b);
}
__device__ __forceinline__ float b2f(ushort_t u) {
  unsigned int x = ((unsigned int)u) << 16;
  return __builtin_bit_cast(float, x);
}
__device__ __forceinline__ void async16(const void* g, void* l) {
  __builtin_amdgcn_global_load_lds(
      (const __attribute__((address_space(1))) unsigned int*)g,
      (__attribute__((address_space(3))) unsigned int*)l, 16, 0, 0);
}

// ---------------------------------------------------------------------------
// 32x32x16 bf16 MFMA NT GEMM (r12): same LDS traffic as the 16x16x32 version
// (8 ds_read_b128 per BK=32 iter) but 8 MFMA @ ~8.07cyc instead of 16 @ ~4.85
// (m119: 32x32 pipe is ~15% faster). Wave-tile 64x(BN/2): MI=2 m-frags x
// NJ=BN/64 n-frags of 32x32, 16 f32 acc regs each.
// A-frag: A[m=lane&31][k=(lane>>5)*8+j] (dual of verified 16x16 layout).
// C/D: col=lane&31, row=(reg&3)+8*(reg>>2)+4*(lane>>5)  [m74/m101 verified].
// XOR swizzle on 16B K-chunks, key (row>>1)&3 — quarter-wave b128 groups
// land 2-way max (free, m136).
// EPI: 0 = f32 store, 1 = bf16 store.
// ---------------------------------------------------------------------------
template <int EPI, int BN>
__global__ __launch_bounds__(256) void gemm32(
    const ushort_t* __restrict__ A, int lda,
    const ushort_t* __restrict__ B, int ldb,
    void* __restrict__ Cv, int ldc, int K)
{
  constexpr int MI = 2;
  constexpr int NJ = BN / 64;          // 2 (BN=128) or 1 (BN=64)
  __shared__ ushort_t As[128 * 32];
  __shared__ ushort_t Bs[BN * 32];
  const int tid  = threadIdx.x;
  const int m0   = blockIdx.y * 128, n0 = blockIdx.x * BN;
  const int lane = tid & 63;
  const int wave = tid >> 6;
  const int wm   = (wave >> 1) * 64, wn = (wave & 1) * (BN / 2);
  const int lm   = lane & 31;          // frag row
  const int kg   = lane >> 5;          // k-group (0/1)
  const int r0 = tid >> 2;
  const int cswz = (((tid & 3) ^ ((r0 >> 1) & 3))) * 8;
  const int key  = (lm >> 1) & 3;

  fx16 acc[MI][NJ] = {};

  const ushort_t* ga = A + (size_t)(m0 + r0) * lda + cswz;
  const ushort_t* gb = B + (size_t)(n0 + r0) * ldb + cswz;
  ushort_t* la0 = &As[r0 * 32 + (tid & 3) * 8];
  ushort_t* la1 = &As[(r0 + 64) * 32 + (tid & 3) * 8];
  ushort_t* lb0 = &Bs[r0 * 32 + (tid & 3) * 8];
  ushort_t* lb1 = (BN == 128) ? &Bs[(r0 + 64) * 32 + (tid & 3) * 8] : nullptr;

  for (int k0 = 0; k0 < K; k0 += 32) {
    async16(ga + k0, la0);
    async16(ga + (size_t)64 * lda + k0, la1);
    async16(gb + k0, lb0);
    if (BN == 128) async16(gb + (size_t)64 * ldb + k0, lb1);
    __syncthreads();

#pragma unroll
    for (int kk = 0; kk < 2; ++kk) {
      const int swz = ((kk * 2 + kg) ^ key) * 8;
      bfx8 af[MI], bfr[NJ];
#pragma unroll
      for (int i = 0; i < MI; ++i)
        af[i] = *(const bfx8*)&As[(wm + i * 32 + lm) * 32 + swz];
#pragma unroll
      for (int j = 0; j < NJ; ++j)
        bfr[j] = *(const bfx8*)&Bs[(wn + j * 32 + lm) * 32 + swz];
#pragma unroll
      for (int i = 0; i < MI; ++i)
#pragma unroll
        for (int j = 0; j < NJ; ++j)
          acc[i][j] = __builtin_amdgcn_mfma_f32_32x32x16_bf16(af[i], bfr[j], acc[i][j], 0, 0, 0);
    }
    __syncthreads();
  }

  // C/D (32x32): col = lane&31, row = (reg&3) + 8*(reg>>2) + 4*(lane>>5)
#pragma unroll
  for (int i = 0; i < MI; ++i)
#pragma unroll
    for (int j = 0; j < NJ; ++j)
#pragma unroll
      for (int r = 0; r < 16; ++r) {
        const int lrow = (r & 3) + 8 * (r >> 2) + 4 * kg;
        const size_t rowoff =
            (size_t)(m0 + wm + i * 32 + lrow) * ldc + n0 + wn + j * 32 + lm;
        if (EPI == 1) ((ushort_t*)Cv)[rowoff] = f2b(acc[i][j][r]);
        else          ((float*)Cv)[rowoff]   = acc[i][j][r];
      }
}

// ---------------------------------------------------------------------------
// 16x16x32 bf16 MFMA NT GEMM (kept for delta-GEMM; N=48-grain dbl below).
// EPI: 2 = bf16 store of softplus(acc+bias[n]).
// NOTE (r6): 128x256 tile regressed (occupancy 10%). NOTE (r8/r10): scan
// fusion (cooperative or flag-synced) regressed ~3x — keep 3-pass scan.
// ---------------------------------------------------------------------------
template <int EPI, int BN>
__global__ __launch_bounds__(256) void gemm_bf16(
    const ushort_t* __restrict__ A, int lda,
    const ushort_t* __restrict__ B, int ldb,
    void* __restrict__ Cv, int ldc, int K,
    const float* __restrict__ bias)
{
  constexpr int NJ = BN / 32;
  __shared__ ushort_t As[128 * 32];
  __shared__ ushort_t Bs[BN * 32];
  const int tid  = threadIdx.x;
  const int m0   = blockIdx.y * 128, n0 = blockIdx.x * BN;
  const int lane = tid & 63;
  const int wave = tid >> 6;
  const int wm   = (wave >> 1) * 64, wn = (wave & 1) * (BN / 2);
  const int lm   = lane & 15;
  const int r0 = tid >> 2;
  const int cswz = (((tid & 3) ^ ((r0 >> 1) & 3))) * 8;
  const int swz = (((lane >> 4) ^ ((lm >> 1) & 3))) * 8;

  fx4 acc[4][NJ] = {};

  const ushort_t* ga = A + (size_t)(m0 + r0) * lda + cswz;
  const ushort_t* gb = B + (size_t)(n0 + r0) * ldb + cswz;
  ushort_t* la0 = &As[r0 * 32 + (tid & 3) * 8];
  ushort_t* la1 = &As[(r0 + 64) * 32 + (tid & 3) * 8];
  ushort_t* lb0 = &Bs[r0 * 32 + (tid & 3) * 8];
  ushort_t* lb1 = (BN == 128) ? &Bs[(r0 + 64) * 32 + (tid & 3) * 8] : nullptr;

  for (int k0 = 0; k0 < K; k0 += 32) {
    async16(ga + k0, la0);
    async16(ga + (size_t)64 * lda + k0, la1);
    async16(gb + k0, lb0);
    if (BN == 128) async16(gb + (size_t)64 * ldb + k0, lb1);
    __syncthreads();

    bfx8 af[4], bfr[NJ];
#pragma unroll
    for (int i = 0; i < 4; ++i)
      af[i] = *(const bfx8*)&As[(wm + i * 16 + lm) * 32 + swz];
#pragma unroll
    for (int j = 0; j < NJ; ++j)
      bfr[j] = *(const bfx8*)&Bs[(wn + j * 16 + lm) * 32 + swz];
#pragma unroll
    for (int i = 0; i < 4; ++i)
#pragma unroll
      for (int j = 0; j < NJ; ++j)
        acc[i][j] = __builtin_amdgcn_mfma_f32_16x16x32_bf16(af[i], bfr[j], acc[i][j], 0, 0, 0);
    __syncthreads();
  }

  const int crow = (lane >> 4) * 4;
  const int ccol = lane & 15;
#pragma unroll
  for (int i = 0; i < 4; ++i)
#pragma unroll
    for (int r = 0; r < 4; ++r) {
      const size_t rowoff = (size_t)(m0 + wm + i * 16 + crow + r) * ldc + n0 + wn + ccol;
      if (EPI == 1) {
        ushort_t* cp = (ushort_t*)Cv + rowoff;
#pragma unroll
        for (int j = 0; j < NJ; ++j) cp[j * 16] = f2b(acc[i][j][r]);
      } else if (EPI == 2) {
        ushort_t* cp = (ushort_t*)Cv + rowoff;
        const int nb = n0 + wn + ccol;
#pragma unroll
        for (int j = 0; j < NJ; ++j)
          cp[j * 16] = f2b(softplusf(acc[i][j][r] + bias[nb + j * 16]));
      } else {
        float* cp = (float*)Cv + rowoff;
#pragma unroll
        for (int j = 0; j < NJ; ++j) cp[j * 16] = acc[i][j][r];
      }
    }
}

// ---------------------------------------------------------------------------
// dbl GEMM: partial[z][L,96] f32 = xsb bf16 @ W_xb bf16^T over K-chunk z.
// ---------------------------------------------------------------------------
__global__ __launch_bounds__(256) void gemm_dbl(
    const ushort_t* __restrict__ A, const ushort_t* __restrict__ B,
    float* __restrict__ P)
{
  __shared__ ushort_t As[128 * 32];
  __shared__ ushort_t Bs[128 * 32];
  const int tid  = threadIdx.x;
  const int m0   = blockIdx.y * 128;
  const int lane = tid & 63;
  const int wave = tid >> 6;
  const int wm   = (wave >> 1) * 64, wn = (wave & 1) * 48;
  const int lm   = lane & 15;
  const int r0 = tid >> 2;
  const int cswz = (((tid & 3) ^ ((r0 >> 1) & 3))) * 8;
  const int swz  = (((lane >> 4) ^ ((lm >> 1) & 3))) * 8;
  const int kbeg = blockIdx.z * (DI / KSPLIT);

  fx4 acc[4][3] = {};

  const int brow1 = (r0 + 64 < DXW) ? r0 + 64 : DXW - 1;  // clamp; rows>=96 unused
  const ushort_t* ga  = A + (size_t)(m0 + r0) * DI + kbeg + cswz;
  const ushort_t* gb0 = B + (size_t)r0 * DI + kbeg + cswz;
  const ushort_t* gb1 = B + (size_t)brow1 * DI + kbeg + cswz;
  ushort_t* la0 = &As[r0 * 32 + (tid & 3) * 8];
  ushort_t* la1 = &As[(r0 + 64) * 32 + (tid & 3) * 8];
  ushort_t* lb0 = &Bs[r0 * 32 + (tid & 3) * 8];
  ushort_t* lb1 = &Bs[(r0 + 64) * 32 + (tid & 3) * 8];

  for (int k0 = 0; k0 < DI / KSPLIT; k0 += 32) {
    async16(ga + k0, la0);
    async16(ga + (size_t)64 * DI + k0, la1);
    async16(gb0 + k0, lb0);
    async16(gb1 + k0, lb1);
    __syncthreads();

    bfx8 af[4], bfr[3];
#pragma unroll
    for (int i = 0; i < 4; ++i)
      af[i] = *(const bfx8*)&As[(wm + i * 16 + lm) * 32 + swz];
#pragma unroll
    for (int j = 0; j < 3; ++j)
      bfr[j] = *(const bfx8*)&Bs[(wn + j * 16 + lm) * 32 + swz];
#pragma unroll
    for (int i = 0; i < 4; ++i)
#pragma unroll
      for (int j = 0; j < 3; ++j)
        acc[i][j] = __builtin_amdgcn_mfma_f32_16x16x32_bf16(af[i], bfr[j], acc[i][j], 0, 0, 0);
    __syncthreads();
  }

  float* base = P + (size_t)blockIdx.z * LSEQ * DXW;
  const int crow = (lane >> 4) * 4;
  const int ccol = lane & 15;
#pragma unroll
  for (int i = 0; i < 4; ++i)
#pragma unroll
    for (int r = 0; r < 4; ++r) {
      float* cp = base + (size_t)(m0 + wm + i * 16 + crow + r) * DXW + wn + ccol;
#pragma unroll
      for (int j = 0; j < 3; ++j)
        cp[j * 16] = acc[i][j][r];
    }
}

// ---------------------------------------------------------------------------
// reduce_dbl: sum KSPLIT partials; emit dtb = bf16(cols 0..63) and
// dblBC = f32 compact (cols 64..95 -> [l][32]). Deterministic z-order.
// ---------------------------------------------------------------------------
__global__ __launch_bounds__(256) void reduce_dbl(
    const float* __restrict__ P, ushort_t* __restrict__ dtb,
    float* __restrict__ dblBC)
{
  const int f = blockIdx.x * 256 + threadIdx.x;     // < LSEQ*DXW
  float s = 0.f;
#pragma unroll
  for (int z = 0; z < KSPLIT; ++z) s += P[(size_t)z * LSEQ * DXW + f];
  const int l = f / DXW;
  const int c = f - l * DXW;
  if (c < DRNK) dtb[(size_t)l * DRNK + c] = f2b(s);
  else          dblBC[(size_t)l * 32 + (c - DRNK)] = s;
}

// ---------------------------------------------------------------------------
// Fused cast of all 5 constant inputs to bf16 (one launch).
// ---------------------------------------------------------------------------
#define CSZ0 (LSEQ * DM)        // x       4194304
#define CSZ1 (2 * DI * DM)      // W_in    4194304
#define CSZ2 (DM * DI)          // W_out   2097152
#define CSZ3 (DXW * DI)         // W_x      196608
#define CSZ4 (DI * DRNK)        // W_dt     131072
#define CTOT (CSZ0 + CSZ1 + CSZ2 + CSZ3 + CSZ4)

__global__ __launch_bounds__(256) void cast_all(
    const float* __restrict__ x, const float* __restrict__ W_in,
    const float* __restrict__ W_out, const float* __restrict__ W_x,
    const float* __restrict__ W_dt,
    ushort_t* __restrict__ xb, ushort_t* __restrict__ W_inb,
    ushort_t* __restrict__ W_outb, ushort_t* __restrict__ W_xb,
    ushort_t* __restrict__ W_dtb)
{
  int i = (blockIdx.x * 256 + threadIdx.x) * 4;
  if (i >= CTOT) return;
  const float* src; ushort_t* dst;
  if (i < CSZ0) { src = x + i; dst = xb + i; }
  else if (i < CSZ0 + CSZ1) { int o = i - CSZ0; src = W_in + o; dst = W_inb + o; }
  else if (i < CSZ0 + CSZ1 + CSZ2) { int o = i - CSZ0 - CSZ1; src = W_out + o; dst = W_outb + o; }
  else if (i < CSZ0 + CSZ1 + CSZ2 + CSZ3) { int o = i - CSZ0 - CSZ1 - CSZ2; src = W_x + o; dst = W_xb + o; }
  else { int o = i - CSZ0 - CSZ1 - CSZ2 - CSZ3; src = W_dt + o; dst = W_dtb + o; }
  float4 v = *(const float4*)src;
  ushort4 o4;
  o4.x = f2b(v.x); o4.y = f2b(v.y); o4.z = f2b(v.z); o4.w = f2b(v.w);
  *(ushort4*)dst = o4;
}

// ---------------------------------------------------------------------------
// Sliding-window depthwise causal conv (k=4) + bias + silu, bf16 in/out.
// ---------------------------------------------------------------------------
__global__ __launch_bounds__(256) void conv2(
    const ushort_t* __restrict__ xrb, const float* __restrict__ cw,
    const float* __restrict__ cb, ushort_t* __restrict__ xsb)
{
  const int d0 = threadIdx.x * 8;
  const int l0 = blockIdx.x * 8;

  float4 w[8];
#pragma unroll
  for (int j = 0; j < 8; ++j) w[j] = *(const float4*)(cw + (size_t)(d0 + j) * DCONV);
  float cbv[8];
  *(float4*)&cbv[0] = *(const float4*)(cb + d0);
  *(float4*)&cbv[4] = *(const float4*)(cb + d0 + 4);

  float h0[8], h1[8], h2[8];
#pragma unroll
  for (int j = 0; j < 8; ++j) { h0[j] = 0.f; h1[j] = 0.f; h2[j] = 0.f; }
  if (l0 >= 3) {
    usx8 u0 = *(const usx8*)(xrb + (size_t)(l0 - 3) * (2 * DI) + d0);
    usx8 u1 = *(const usx8*)(xrb + (size_t)(l0 - 2) * (2 * DI) + d0);
    usx8 u2 = *(const usx8*)(xrb + (size_t)(l0 - 1) * (2 * DI) + d0);
#pragma unroll
    for (int j = 0; j < 8; ++j) { h0[j] = b2f(u0[j]); h1[j] = b2f(u1[j]); h2[j] = b2f(u2[j]); }
  }

#pragma unroll
  for (int i = 0; i < 8; ++i) {
    const int l = l0 + i;
    usx8 uc = *(const usx8*)(xrb + (size_t)l * (2 * DI) + d0);
    float c[8];
#pragma unroll
    for (int j = 0; j < 8; ++j) c[j] = b2f(uc[j]);
    usx8 o;
#pragma unroll
    for (int j = 0; j < 8; ++j) {
      float acc = cbv[j];
      acc = fmaf(w[j].x, h0[j], acc);
      acc = fmaf(w[j].y, h1[j], acc);
      acc = fmaf(w[j].z, h2[j], acc);
      acc = fmaf(w[j].w, c[j], acc);
      o[j] = f2b(siluf(acc));
    }
    *(usx8*)(xsb + (size_t)l * DI + d0) = o;
#pragma unroll
    for (int j = 0; j < 8; ++j) { h0[j] = h1[j]; h1[j] = h2[j]; h2[j] = c[j]; }
  }
}

// ---------------------------------------------------------------------------
// Chain detector: S4D-real init gives Av[n] = -(n+1) exactly, so
// dA[n] = q^(n+1), q = exp(-dlt): 1 exp + 16 muls instead of 16 exps.
// ---------------------------------------------------------------------------
__device__ __forceinline__ bool chain_ok(const float* Av) {
  bool ok = true;
#pragma unroll
  for (int n = 0; n < DSTATE; ++n)
    ok = ok && (fabsf(Av[n] + (float)(n + 1)) < 1e-4f);
  return ok;
}

// ---------------------------------------------------------------------------
// Scan pass 1 (LDS-staged): local scan (h=0), emit P=prod(dA), S=end state.
// ---------------------------------------------------------------------------
__global__ __launch_bounds__(256) void scan_pass1(
    const ushort_t* __restrict__ deltab, const ushort_t* __restrict__ xsb,
    const float* __restrict__ dblBC, const float* __restrict__ A_log,
    float* __restrict__ cP, float* __restrict__ cS)
{
  const int tid = threadIdx.x;
  const int g = blockIdx.x;            // dgroup (256 d's)
  const int c = blockIdx.y;            // chunk
  const int d = g * 256 + tid;
  __shared__ ushort_t Dsh[CLEN * 256];
  __shared__ ushort_t Ush[CLEN * 256];
  __shared__ float Bsh[CLEN][DSTATE];

  const size_t rowbase = (size_t)(c * CLEN) * DI + g * 256;
  for (int i = tid; i < CLEN * 32; i += 256) {
    const int l = i >> 5;
    const int o = (i & 31) * 8;
    *(usx8*)&Dsh[l * 256 + o] = *(const usx8*)(deltab + rowbase + (size_t)l * DI + o);
    *(usx8*)&Ush[l * 256 + o] = *(const usx8*)(xsb   + rowbase + (size_t)l * DI + o);
  }
  for (int i = tid; i < CLEN * DSTATE; i += 256) {
    const int l = i >> 4, n = i & 15;
    Bsh[l][n] = dblBC[(size_t)(c * CLEN + l) * 32 + n];
  }
  __syncthreads();

  float Av[DSTATE], h[DSTATE];
#pragma unroll
  for (int n = 0; n < DSTATE; ++n) {
    Av[n] = -__expf(A_log[d * DSTATE + n]);
    h[n] = 0.f;
  }
  const size_t base = (size_t)c * DI * DSTATE + (size_t)d * DSTATE;

  if (chain_ok(Av)) {
    float sd = 0.f;
    for (int l = 0; l < CLEN; ++l) {
      const float dlt = b2f(Dsh[l * 256 + tid]);
      const float du = dlt * b2f(Ush[l * 256 + tid]);
      sd += dlt;
      const float q = __expf(-dlt);
      float dAn = 1.f;
#pragma unroll
      for (int n = 0; n < DSTATE; ++n) {
        dAn *= q;
        h[n] = fmaf(dAn, h[n], du * Bsh[l][n]);
      }
    }
    const float Qc = __expf(-sd);
    float Pn = 1.f;
#pragma unroll
    for (int n = 0; n < DSTATE; ++n) {
      Pn *= Qc;
      cP[base + n] = Pn; cS[base + n] = h[n];
    }
  } else {
    float P[DSTATE];
#pragma unroll
    for (int n = 0; n < DSTATE; ++n) P[n] = 1.f;
    for (int l = 0; l < CLEN; ++l) {
      const float dlt = b2f(Dsh[l * 256 + tid]);
      const float du = dlt * b2f(Ush[l * 256 + tid]);
#pragma unroll
      for (int n = 0; n < DSTATE; ++n) {
        const float dA = __expf(dlt * Av[n]);
        h[n] = fmaf(dA, h[n], du * Bsh[l][n]);
        P[n] *= dA;
      }
    }
#pragma unroll
    for (int n = 0; n < DSTATE; ++n) { cP[base + n] = P[n]; cS[base + n] = h[n]; }
  }
}

// ---------------------------------------------------------------------------
// Scan pass 2: sequential carry over chunks; ch0 may alias cP.
// ---------------------------------------------------------------------------
__global__ __launch_bounds__(256) void scan_pass2(
    const float* __restrict__ cP, const float* __restrict__ cS,
    float* __restrict__ ch0)
{
  const int dn = blockIdx.x * 256 + threadIdx.x;
  float h = 0.f;
  for (int c = 0; c < NCH; ++c) {
    const size_t o = (size_t)c * DI * DSTATE + dn;
    const float p = cP[o], s = cS[o];
    ch0[o] = h;
    h = fmaf(p, h, s);
  }
}

// ---------------------------------------------------------------------------
// Scan pass 3 (LDS-staged) + gate: y1b = bf16( (scan_y + u*D) * silu(res) ).
// ---------------------------------------------------------------------------
__global__ __launch_bounds__(256) void scan_pass3(
    const ushort_t* __restrict__ deltab, const ushort_t* __restrict__ xsb,
    const float* __restrict__ dblBC, const float* __restrict__ A_log,
    const float* __restrict__ ch0, const float* __restrict__ Dp,
    const ushort_t* __restrict__ xrb, ushort_t* __restrict__ y1b)
{
  const int tid = threadIdx.x;
  const int g = blockIdx.x;
  const int c = blockIdx.y;
  const int d = g * 256 + tid;
  __shared__ ushort_t Dsh[CLEN * 256];
  __shared__ ushort_t Ush[CLEN * 256];
  __shared__ float Bsh[CLEN][DSTATE];
  __shared__ float Csh[CLEN][DSTATE];

  const size_t rowbase = (size_t)(c * CLEN) * DI + g * 256;
  for (int i = tid; i < CLEN * 32; i += 256) {
    const int l = i >> 5;
    const int o = (i & 31) * 8;
    *(usx8*)&Dsh[l * 256 + o] = *(const usx8*)(deltab + rowbase + (size_t)l * DI + o);
    *(usx8*)&Ush[l * 256 + o] = *(const usx8*)(xsb   + rowbase + (size_t)l * DI + o);
  }
  for (int i = tid; i < CLEN * DSTATE; i += 256) {
    const int l = i >> 4, n = i & 15;
    const size_t row = (size_t)(c * CLEN + l) * 32;
    Bsh[l][n] = dblBC[row + n];
    Csh[l][n] = dblBC[row + 16 + n];
  }
  __syncthreads();

  float Av[DSTATE], h[DSTATE];
  const size_t base = (size_t)c * DI * DSTATE + (size_t)d * DSTATE;
#pragma unroll
  for (int n = 0; n < DSTATE; ++n) {
    Av[n] = -__expf(A_log[d * DSTATE + n]);
    h[n] = ch0[base + n];
  }
  const float Dd = Dp[d];
  const ushort_t* resp = xrb + (size_t)(c * CLEN) * (2 * DI) + DI + d;
  ushort_t* yp = y1b + (size_t)(c * CLEN) * DI + d;

  if (chain_ok(Av)) {
    for (int l = 0; l < CLEN; ++l) {
      const float dlt = b2f(Dsh[l * 256 + tid]);
      const float u = b2f(Ush[l * 256 + tid]);
      const float du = dlt * u;
      const float q = __expf(-dlt);
      float dAn = 1.f;
      float y = 0.f;
#pragma unroll
      for (int n = 0; n < DSTATE; ++n) {
        dAn *= q;
        h[n] = fmaf(dAn, h[n], du * Bsh[l][n]);
        y = fmaf(h[n], Csh[l][n], y);
      }
      y = fmaf(u, Dd, y);
      const float res = b2f(resp[(size_t)l * (2 * DI)]);
      yp[(size_t)l * DI] = f2b(y * siluf(res));
    }
  } else {
    for (int l = 0; l < CLEN; ++l) {
      const float dlt = b2f(Dsh[l * 256 + tid]);
      const float u = b2f(Ush[l * 256 + tid]);
      const float du = dlt * u;
      float y = 0.f;
#pragma unroll
      for (int n = 0; n < DSTATE; ++n) {
        const float dA = __expf(dlt * Av[n]);
        h[n] = fmaf(dA, h[n], du * Bsh[l][n]);
        y = fmaf(h[n], Csh[l][n], y);
      }
      y = fmaf(u, Dd, y);
      const float res = b2f(resp[(size_t)l * (2 * DI)]);
      yp[(size_t)l * DI] = f2b(y * siluf(res));
    }
  }
}

// ---------------------------------------------------------------------------
extern "C" void kernel_launch(void* const* d_in, const int* in_sizes, int n_in,
                              void* d_out, int out_size, void* d_ws, size_t ws_size,
                              hipStream_t stream) {
  (void)in_sizes; (void)n_in; (void)out_size; (void)ws_size;
  const float* x      = (const float*)d_in[0];
  const float* W_in   = (const float*)d_in[1];
  const float* conv_w = (const float*)d_in[2];
  const float* conv_b = (const float*)d_in[3];
  const float* W_x    = (const float*)d_in[4];
  const float* W_dt   = (const float*)d_in[5];
  const float* b_dt   = (const float*)d_in[6];
  const float* A_log  = (const float*)d_in[7];
  const float* Dp     = (const float*)d_in[8];
  const float* W_out  = (const float*)d_in[9];
  float* out = (float*)d_out;

  // workspace layout (r9 config).
  // partial (KSPLIT*L*96 f = 12.6 MB) aliases [cP, cS] (16.8 MB):
  //   gemm_dbl writes partial -> reduce_dbl consumes -> delta-GEMM ->
  //   scan_pass1 writes cP/cS. No live overlap.
  float* ws    = (float*)d_ws;
  float* cP    = ws;                                   // 2.1M f
  float* cS    = cP + (size_t)NCH * DI * DSTATE;       // 2.1M f
  ushort_t* deltab = (ushort_t*)(cS + (size_t)NCH * DI * DSTATE);  // L*DI bf16
  ushort_t* xrb   = deltab + (size_t)LSEQ * DI;        // L*2DI
  ushort_t* xsb   = xrb   + (size_t)LSEQ * 2 * DI;     // L*DI
  ushort_t* y1b   = xsb   + (size_t)LSEQ * DI;         // L*DI
  ushort_t* xb    = y1b   + (size_t)LSEQ * DI;         // L*DM
  ushort_t* W_inb = xb    + (size_t)LSEQ * DM;         // 2DI*DM
  ushort_t* W_outb= W_inb + (size_t)2 * DI * DM;       // DM*DI
  ushort_t* W_xb  = W_outb+ (size_t)DM * DI;           // 96*DI
  ushort_t* W_dtb = W_xb  + (size_t)DXW * DI;          // DI*64
  ushort_t* dtb   = W_dtb + (size_t)DI * DRNK;         // L*64
  float* dblBC = (float*)(dtb + (size_t)LSEQ * DRNK);  // L*32 f
  float* partial = cP;   // alias (see above)
  float* ch0 = cP;       // alias (in-place in scan_pass2)

  // 0) all input casts in one launch
  hipLaunchKernelGGL(cast_all, dim3((CTOT / 4 + 255) / 256), dim3(256), 0, stream,
                     x, W_in, W_out, W_x, W_dt, xb, W_inb, W_outb, W_xb, W_dtb);

  // 1) xrb = bf16(x @ W_in.T)  (M=4096, N=4096, K=1024), 32x32x16 frags
  hipLaunchKernelGGL(HIP_KERNEL_NAME(gemm32<1, 128>),
                     dim3((2 * DI) / 128, LSEQ / 128), dim3(256), 0, stream,
                     xb, DM, W_inb, DM, (void*)xrb, 2 * DI, DM);

  // 2) xsb = bf16(silu(conv(xi) + b)) — sliding window
  hipLaunchKernelGGL(conv2, dim3(LSEQ / 8), dim3(256), 0, stream,
                     xrb, conv_w, conv_b, xsb);

  // 3) partial[z] = xsb @ W_xb.T chunk z; then reduce -> dtb bf16 + dblBC f32
  hipLaunchKernelGGL(gemm_dbl, dim3(1, LSEQ / 128, KSPLIT), dim3(256), 0, stream,
                     xsb, W_xb, partial);
  hipLaunchKernelGGL(reduce_dbl, dim3((LSEQ * DXW) / 256), dim3(256), 0, stream,
                     partial, dtb, dblBC);

  // 4) deltab = bf16(softplus(dtb @ W_dtb.T + b_dt))  (K=64)
  hipLaunchKernelGGL(HIP_KERNEL_NAME(gemm_bf16<2, 128>),
                     dim3(DI / 128, LSEQ / 128), dim3(256), 0, stream,
                     dtb, DRNK, W_dtb, DRNK, (void*)deltab, DI, DRNK, b_dt);

  // 5) chunked selective scan (3-pass, CLEN=64 — r9 config, validated optimum)
  hipLaunchKernelGGL(scan_pass1, dim3(DI / 256, NCH), dim3(256), 0, stream,
                     deltab, xsb, dblBC, A_log, cP, cS);
  hipLaunchKernelGGL(scan_pass2, dim3((DI * DSTATE) / 256), dim3(256), 0, stream,
                     cP, cS, ch0);
  hipLaunchKernelGGL(scan_pass3, dim3(DI / 256, NCH), dim3(256), 0, stream,
                     deltab, xsb, dblBC, A_log, ch0, Dp, xrb, y1b);

  // 6) out = y1b @ W_out.T  (M=4096, N=1024, K=2048), 32x32x16 frags, 128x64
  hipLaunchKernelGGL(HIP_KERNEL_NAME(gemm32<0, 64>),
                     dim3(DM / 64, LSEQ / 128), dim3(256), 0, stream,
                     y1b, DI, W_outb, DI, (void*)out, DM, DI);
}

// Round 13
// 294.273 us; speedup vs baseline: 1.4188x; 1.0281x over previous
//
#include <hip/hip_runtime.h>
#include <cstdint>
#include <cstddef>

// Problem constants
#define LSEQ 4096
#define DM 1024
#define DI 2048
#define DCONV 4
#define DRNK 64
#define DSTATE 16
#define DXW 96        // DRNK + 2*DSTATE
#define NCH 64        // r11: CLEN=32/NCH=128 regressed (315 vs 309) — keep 64
#define CLEN 64       // LSEQ / NCH
#define KSPLIT 8      // split-K for dbl GEMM (r9 config)

typedef unsigned short ushort_t;
typedef __bf16 bfx8 __attribute__((ext_vector_type(8)));
typedef float  fx4  __attribute__((ext_vector_type(4)));
typedef float  fx16 __attribute__((ext_vector_type(16)));
typedef ushort_t usx8 __attribute__((ext_vector_type(8)));

__device__ __forceinline__ float siluf(float x) { return x / (1.f + __expf(-x)); }
__device__ __forceinline__ float softplusf(float x) {
  return fmaxf(x, 0.f) + log1pf(__expf(-fabsf(x)));
}
__device__ __forceinline__ ushort_t f2b(float x) {
  __bf16 b = (__bf16)x;   // RNE
  return __builtin_bit_cast(ushort_t, b);
}
__device__ __forceinline__ float b2f(ushort_t u) {
  unsigned int x = ((unsigned int)u) << 16;
  return __builtin_bit_cast(float, x);
}
__device__ __forceinline__ void async16(const void* g, void* l) {
  __builtin_amdgcn_global_load_lds(
      (const __attribute__((address_space(1))) unsigned int*)g,
      (__attribute__((address_space(3))) unsigned int*)l, 16, 0, 0);
}

// ---------------------------------------------------------------------------
// 32x32x16 bf16 MFMA NT GEMM, BK=64 (r13): halves the per-iter barrier drain
// (the ~20% s_waitcnt vmcnt(0)+s_barrier cost of the m97 structure) at the
// same staged bytes and MFMA count. LDS row = 128B: 3-bit XOR swizzle
// (chunk ^ row&7) — 8 consecutive lanes hit 8 distinct 16B slots, provably
// conflict-free. LDS 32KB (BN=128) / 24KB (BN=64) — occupancy unchanged.
// Wave-tile 64x(BN/2): MI=2 x NJ=BN/64 frags of 32x32, 16 f32 acc each.
// C/D: col=lane&31, row=(reg&3)+8*(reg>>2)+4*(lane>>5)  [m74/m101 verified].
// NOTE (r6): 128x256 tile regressed (occupancy). NOTE (r12): 32x32x16 frags
// beat 16x16x32 by ~8% (55.0 vs 59.5us on GEMM-1).
// EPI: 0 = f32 store, 1 = bf16 store.
// ---------------------------------------------------------------------------
template <int EPI, int BN>
__global__ __launch_bounds__(256) void gemm32(
    const ushort_t* __restrict__ A, int lda,
    const ushort_t* __restrict__ B, int ldb,
    void* __restrict__ Cv, int ldc, int K)
{
  constexpr int MI = 2;
  constexpr int NJ = BN / 64;          // 2 (BN=128) or 1 (BN=64)
  __shared__ ushort_t As[128 * 64];
  __shared__ ushort_t Bs[BN * 64];
  const int tid  = threadIdx.x;
  const int m0   = blockIdx.y * 128, n0 = blockIdx.x * BN;
  const int lane = tid & 63;
  const int wave = tid >> 6;
  const int wm   = (wave >> 1) * 64, wn = (wave & 1) * (BN / 2);
  const int lm   = lane & 31;          // frag row
  const int kg   = lane >> 5;          // k-group (0/1)
  // staging: r0 = tid>>3 (0..31 rows/issue), pos = tid&7 (16B slot in row);
  // slot pos of row r holds global chunk pos ^ (r&7)
  const int r0  = tid >> 3;
  const int pos = tid & 7;
  const int cswz = (pos ^ (r0 & 7)) * 8;   // element offset into global row
  const int key  = lm & 7;                 // read-side swizzle key (= row&7)

  fx16 acc[MI][NJ] = {};

  const ushort_t* ga = A + (size_t)(m0 + r0) * lda + cswz;
  const ushort_t* gb = B + (size_t)(n0 + r0) * ldb + cswz;

  for (int k0 = 0; k0 < K; k0 += 64) {
#pragma unroll
    for (int t = 0; t < 4; ++t)
      async16(ga + (size_t)(32 * t) * lda + k0, &As[t * 32 * 64 + tid * 8]);
#pragma unroll
    for (int t = 0; t < BN / 32; ++t)
      async16(gb + (size_t)(32 * t) * ldb + k0, &Bs[t * 32 * 64 + tid * 8]);
    __syncthreads();

#pragma unroll
    for (int kk = 0; kk < 4; ++kk) {
      const int swz = ((kk * 2 + kg) ^ key) * 8;
      bfx8 af[MI], bfr[NJ];
#pragma unroll
      for (int i = 0; i < MI; ++i)
        af[i] = *(const bfx8*)&As[(wm + i * 32 + lm) * 64 + swz];
#pragma unroll
      for (int j = 0; j < NJ; ++j)
        bfr[j] = *(const bfx8*)&Bs[(wn + j * 32 + lm) * 64 + swz];
#pragma unroll
      for (int i = 0; i < MI; ++i)
#pragma unroll
        for (int j = 0; j < NJ; ++j)
          acc[i][j] = __builtin_amdgcn_mfma_f32_32x32x16_bf16(af[i], bfr[j], acc[i][j], 0, 0, 0);
    }
    __syncthreads();
  }

  // C/D (32x32): col = lane&31, row = (reg&3) + 8*(reg>>2) + 4*(lane>>5)
#pragma unroll
  for (int i = 0; i < MI; ++i)
#pragma unroll
    for (int j = 0; j < NJ; ++j)
#pragma unroll
      for (int r = 0; r < 16; ++r) {
        const int lrow = (r & 3) + 8 * (r >> 2) + 4 * kg;
        const size_t rowoff =
            (size_t)(m0 + wm + i * 32 + lrow) * ldc + n0 + wn + j * 32 + lm;
        if (EPI == 1) ((ushort_t*)Cv)[rowoff] = f2b(acc[i][j][r]);
        else          ((float*)Cv)[rowoff]   = acc[i][j][r];
      }
}

// ---------------------------------------------------------------------------
// 16x16x32 bf16 MFMA NT GEMM, BK=32 (kept for delta-GEMM).
// EPI: 2 = bf16 store of softplus(acc+bias[n]).
// NOTE (r8/r10): scan fusion (cooperative or flag-synced) regressed ~3x.
// ---------------------------------------------------------------------------
template <int EPI, int BN>
__global__ __launch_bounds__(256) void gemm_bf16(
    const ushort_t* __restrict__ A, int lda,
    const ushort_t* __restrict__ B, int ldb,
    void* __restrict__ Cv, int ldc, int K,
    const float* __restrict__ bias)
{
  constexpr int NJ = BN / 32;
  __shared__ ushort_t As[128 * 32];
  __shared__ ushort_t Bs[BN * 32];
  const int tid  = threadIdx.x;
  const int m0   = blockIdx.y * 128, n0 = blockIdx.x * BN;
  const int lane = tid & 63;
  const int wave = tid >> 6;
  const int wm   = (wave >> 1) * 64, wn = (wave & 1) * (BN / 2);
  const int lm   = lane & 15;
  const int r0 = tid >> 2;
  const int cswz = (((tid & 3) ^ ((r0 >> 1) & 3))) * 8;
  const int swz = (((lane >> 4) ^ ((lm >> 1) & 3))) * 8;

  fx4 acc[4][NJ] = {};

  const ushort_t* ga = A + (size_t)(m0 + r0) * lda + cswz;
  const ushort_t* gb = B + (size_t)(n0 + r0) * ldb + cswz;
  ushort_t* la0 = &As[r0 * 32 + (tid & 3) * 8];
  ushort_t* la1 = &As[(r0 + 64) * 32 + (tid & 3) * 8];
  ushort_t* lb0 = &Bs[r0 * 32 + (tid & 3) * 8];
  ushort_t* lb1 = (BN == 128) ? &Bs[(r0 + 64) * 32 + (tid & 3) * 8] : nullptr;

  for (int k0 = 0; k0 < K; k0 += 32) {
    async16(ga + k0, la0);
    async16(ga + (size_t)64 * lda + k0, la1);
    async16(gb + k0, lb0);
    if (BN == 128) async16(gb + (size_t)64 * ldb + k0, lb1);
    __syncthreads();

    bfx8 af[4], bfr[NJ];
#pragma unroll
    for (int i = 0; i < 4; ++i)
      af[i] = *(const bfx8*)&As[(wm + i * 16 + lm) * 32 + swz];
#pragma unroll
    for (int j = 0; j < NJ; ++j)
      bfr[j] = *(const bfx8*)&Bs[(wn + j * 16 + lm) * 32 + swz];
#pragma unroll
    for (int i = 0; i < 4; ++i)
#pragma unroll
      for (int j = 0; j < NJ; ++j)
        acc[i][j] = __builtin_amdgcn_mfma_f32_16x16x32_bf16(af[i], bfr[j], acc[i][j], 0, 0, 0);
    __syncthreads();
  }

  const int crow = (lane >> 4) * 4;
  const int ccol = lane & 15;
#pragma unroll
  for (int i = 0; i < 4; ++i)
#pragma unroll
    for (int r = 0; r < 4; ++r) {
      const size_t rowoff = (size_t)(m0 + wm + i * 16 + crow + r) * ldc + n0 + wn + ccol;
      if (EPI == 1) {
        ushort_t* cp = (ushort_t*)Cv + rowoff;
#pragma unroll
        for (int j = 0; j < NJ; ++j) cp[j * 16] = f2b(acc[i][j][r]);
      } else if (EPI == 2) {
        ushort_t* cp = (ushort_t*)Cv + rowoff;
        const int nb = n0 + wn + ccol;
#pragma unroll
        for (int j = 0; j < NJ; ++j)
          cp[j * 16] = f2b(softplusf(acc[i][j][r] + bias[nb + j * 16]));
      } else {
        float* cp = (float*)Cv + rowoff;
#pragma unroll
        for (int j = 0; j < NJ; ++j) cp[j * 16] = acc[i][j][r];
      }
    }
}

// ---------------------------------------------------------------------------
// dbl GEMM: partial[z][L,96] f32 = xsb bf16 @ W_xb bf16^T over K-chunk z.
// ---------------------------------------------------------------------------
__global__ __launch_bounds__(256) void gemm_dbl(
    const ushort_t* __restrict__ A, const ushort_t* __restrict__ B,
    float* __restrict__ P)
{
  __shared__ ushort_t As[128 * 32];
  __shared__ ushort_t Bs[128 * 32];
  const int tid  = threadIdx.x;
  const int m0   = blockIdx.y * 128;
  const int lane = tid & 63;
  const int wave = tid >> 6;
  const int wm   = (wave >> 1) * 64, wn = (wave & 1) * 48;
  const int lm   = lane & 15;
  const int r0 = tid >> 2;
  const int cswz = (((tid & 3) ^ ((r0 >> 1) & 3))) * 8;
  const int swz  = (((lane >> 4) ^ ((lm >> 1) & 3))) * 8;
  const int kbeg = blockIdx.z * (DI / KSPLIT);

  fx4 acc[4][3] = {};

  const int brow1 = (r0 + 64 < DXW) ? r0 + 64 : DXW - 1;  // clamp; rows>=96 unused
  const ushort_t* ga  = A + (size_t)(m0 + r0) * DI + kbeg + cswz;
  const ushort_t* gb0 = B + (size_t)r0 * DI + kbeg + cswz;
  const ushort_t* gb1 = B + (size_t)brow1 * DI + kbeg + cswz;
  ushort_t* la0 = &As[r0 * 32 + (tid & 3) * 8];
  ushort_t* la1 = &As[(r0 + 64) * 32 + (tid & 3) * 8];
  ushort_t* lb0 = &Bs[r0 * 32 + (tid & 3) * 8];
  ushort_t* lb1 = &Bs[(r0 + 64) * 32 + (tid & 3) * 8];

  for (int k0 = 0; k0 < DI / KSPLIT; k0 += 32) {
    async16(ga + k0, la0);
    async16(ga + (size_t)64 * DI + k0, la1);
    async16(gb0 + k0, lb0);
    async16(gb1 + k0, lb1);
    __syncthreads();

    bfx8 af[4], bfr[3];
#pragma unroll
    for (int i = 0; i < 4; ++i)
      af[i] = *(const bfx8*)&As[(wm + i * 16 + lm) * 32 + swz];
#pragma unroll
    for (int j = 0; j < 3; ++j)
      bfr[j] = *(const bfx8*)&Bs[(wn + j * 16 + lm) * 32 + swz];
#pragma unroll
    for (int i = 0; i < 4; ++i)
#pragma unroll
      for (int j = 0; j < 3; ++j)
        acc[i][j] = __builtin_amdgcn_mfma_f32_16x16x32_bf16(af[i], bfr[j], acc[i][j], 0, 0, 0);
    __syncthreads();
  }

  float* base = P + (size_t)blockIdx.z * LSEQ * DXW;
  const int crow = (lane >> 4) * 4;
  const int ccol = lane & 15;
#pragma unroll
  for (int i = 0; i < 4; ++i)
#pragma unroll
    for (int r = 0; r < 4; ++r) {
      float* cp = base + (size_t)(m0 + wm + i * 16 + crow + r) * DXW + wn + ccol;
#pragma unroll
      for (int j = 0; j < 3; ++j)
        cp[j * 16] = acc[i][j][r];
    }
}

// ---------------------------------------------------------------------------
// reduce_dbl: sum KSPLIT partials; emit dtb = bf16(cols 0..63) and
// dblBC = f32 compact (cols 64..95 -> [l][32]). Deterministic z-order.
// ---------------------------------------------------------------------------
__global__ __launch_bounds__(256) void reduce_dbl(
    const float* __restrict__ P, ushort_t* __restrict__ dtb,
    float* __restrict__ dblBC)
{
  const int f = blockIdx.x * 256 + threadIdx.x;     // < LSEQ*DXW
  float s = 0.f;
#pragma unroll
  for (int z = 0; z < KSPLIT; ++z) s += P[(size_t)z * LSEQ * DXW + f];
  const int l = f / DXW;
  const int c = f - l * DXW;
  if (c < DRNK) dtb[(size_t)l * DRNK + c] = f2b(s);
  else          dblBC[(size_t)l * 32 + (c - DRNK)] = s;
}

// ---------------------------------------------------------------------------
// Fused cast of all 5 constant inputs to bf16 (one launch).
// ---------------------------------------------------------------------------
#define CSZ0 (LSEQ * DM)        // x       4194304
#define CSZ1 (2 * DI * DM)      // W_in    4194304
#define CSZ2 (DM * DI)          // W_out   2097152
#define CSZ3 (DXW * DI)         // W_x      196608
#define CSZ4 (DI * DRNK)        // W_dt     131072
#define CTOT (CSZ0 + CSZ1 + CSZ2 + CSZ3 + CSZ4)

__global__ __launch_bounds__(256) void cast_all(
    const float* __restrict__ x, const float* __restrict__ W_in,
    const float* __restrict__ W_out, const float* __restrict__ W_x,
    const float* __restrict__ W_dt,
    ushort_t* __restrict__ xb, ushort_t* __restrict__ W_inb,
    ushort_t* __restrict__ W_outb, ushort_t* __restrict__ W_xb,
    ushort_t* __restrict__ W_dtb)
{
  int i = (blockIdx.x * 256 + threadIdx.x) * 4;
  if (i >= CTOT) return;
  const float* src; ushort_t* dst;
  if (i < CSZ0) { src = x + i; dst = xb + i; }
  else if (i < CSZ0 + CSZ1) { int o = i - CSZ0; src = W_in + o; dst = W_inb + o; }
  else if (i < CSZ0 + CSZ1 + CSZ2) { int o = i - CSZ0 - CSZ1; src = W_out + o; dst = W_outb + o; }
  else if (i < CSZ0 + CSZ1 + CSZ2 + CSZ3) { int o = i - CSZ0 - CSZ1 - CSZ2; src = W_x + o; dst = W_xb + o; }
  else { int o = i - CSZ0 - CSZ1 - CSZ2 - CSZ3; src = W_dt + o; dst = W_dtb + o; }
  float4 v = *(const float4*)src;
  ushort4 o4;
  o4.x = f2b(v.x); o4.y = f2b(v.y); o4.z = f2b(v.z); o4.w = f2b(v.w);
  *(ushort4*)dst = o4;
}

// ---------------------------------------------------------------------------
// Sliding-window depthwise causal conv (k=4) + bias + silu, bf16 in/out.
// ---------------------------------------------------------------------------
__global__ __launch_bounds__(256) void conv2(
    const ushort_t* __restrict__ xrb, const float* __restrict__ cw,
    const float* __restrict__ cb, ushort_t* __restrict__ xsb)
{
  const int d0 = threadIdx.x * 8;
  const int l0 = blockIdx.x * 8;

  float4 w[8];
#pragma unroll
  for (int j = 0; j < 8; ++j) w[j] = *(const float4*)(cw + (size_t)(d0 + j) * DCONV);
  float cbv[8];
  *(float4*)&cbv[0] = *(const float4*)(cb + d0);
  *(float4*)&cbv[4] = *(const float4*)(cb + d0 + 4);

  float h0[8], h1[8], h2[8];
#pragma unroll
  for (int j = 0; j < 8; ++j) { h0[j] = 0.f; h1[j] = 0.f; h2[j] = 0.f; }
  if (l0 >= 3) {
    usx8 u0 = *(const usx8*)(xrb + (size_t)(l0 - 3) * (2 * DI) + d0);
    usx8 u1 = *(const usx8*)(xrb + (size_t)(l0 - 2) * (2 * DI) + d0);
    usx8 u2 = *(const usx8*)(xrb + (size_t)(l0 - 1) * (2 * DI) + d0);
#pragma unroll
    for (int j = 0; j < 8; ++j) { h0[j] = b2f(u0[j]); h1[j] = b2f(u1[j]); h2[j] = b2f(u2[j]); }
  }

#pragma unroll
  for (int i = 0; i < 8; ++i) {
    const int l = l0 + i;
    usx8 uc = *(const usx8*)(xrb + (size_t)l * (2 * DI) + d0);
    float c[8];
#pragma unroll
    for (int j = 0; j < 8; ++j) c[j] = b2f(uc[j]);
    usx8 o;
#pragma unroll
    for (int j = 0; j < 8; ++j) {
      float acc = cbv[j];
      acc = fmaf(w[j].x, h0[j], acc);
      acc = fmaf(w[j].y, h1[j], acc);
      acc = fmaf(w[j].z, h2[j], acc);
      acc = fmaf(w[j].w, c[j], acc);
      o[j] = f2b(siluf(acc));
    }
    *(usx8*)(xsb + (size_t)l * DI + d0) = o;
#pragma unroll
    for (int j = 0; j < 8; ++j) { h0[j] = h1[j]; h1[j] = h2[j]; h2[j] = c[j]; }
  }
}

// ---------------------------------------------------------------------------
// Chain detector: S4D-real init gives Av[n] = -(n+1) exactly, so
// dA[n] = q^(n+1), q = exp(-dlt): 1 exp + 16 muls instead of 16 exps.
// ---------------------------------------------------------------------------
__device__ __forceinline__ bool chain_ok(const float* Av) {
  bool ok = true;
#pragma unroll
  for (int n = 0; n < DSTATE; ++n)
    ok = ok && (fabsf(Av[n] + (float)(n + 1)) < 1e-4f);
  return ok;
}

// ---------------------------------------------------------------------------
// Scan pass 1 (LDS-staged): local scan (h=0), emit P=prod(dA), S=end state.
// ---------------------------------------------------------------------------
__global__ __launch_bounds__(256) void scan_pass1(
    const ushort_t* __restrict__ deltab, const ushort_t* __restrict__ xsb,
    const float* __restrict__ dblBC, const float* __restrict__ A_log,
    float* __restrict__ cP, float* __restrict__ cS)
{
  const int tid = threadIdx.x;
  const int g = blockIdx.x;            // dgroup (256 d's)
  const int c = blockIdx.y;            // chunk
  const int d = g * 256 + tid;
  __shared__ ushort_t Dsh[CLEN * 256];
  __shared__ ushort_t Ush[CLEN * 256];
  __shared__ float Bsh[CLEN][DSTATE];

  const size_t rowbase = (size_t)(c * CLEN) * DI + g * 256;
  for (int i = tid; i < CLEN * 32; i += 256) {
    const int l = i >> 5;
    const int o = (i & 31) * 8;
    *(usx8*)&Dsh[l * 256 + o] = *(const usx8*)(deltab + rowbase + (size_t)l * DI + o);
    *(usx8*)&Ush[l * 256 + o] = *(const usx8*)(xsb   + rowbase + (size_t)l * DI + o);
  }
  for (int i = tid; i < CLEN * DSTATE; i += 256) {
    const int l = i >> 4, n = i & 15;
    Bsh[l][n] = dblBC[(size_t)(c * CLEN + l) * 32 + n];
  }
  __syncthreads();

  float Av[DSTATE], h[DSTATE];
#pragma unroll
  for (int n = 0; n < DSTATE; ++n) {
    Av[n] = -__expf(A_log[d * DSTATE + n]);
    h[n] = 0.f;
  }
  const size_t base = (size_t)c * DI * DSTATE + (size_t)d * DSTATE;

  if (chain_ok(Av)) {
    float sd = 0.f;
    for (int l = 0; l < CLEN; ++l) {
      const float dlt = b2f(Dsh[l * 256 + tid]);
      const float du = dlt * b2f(Ush[l * 256 + tid]);
      sd += dlt;
      const float q = __expf(-dlt);
      float dAn = 1.f;
#pragma unroll
      for (int n = 0; n < DSTATE; ++n) {
        dAn *= q;
        h[n] = fmaf(dAn, h[n], du * Bsh[l][n]);
      }
    }
    const float Qc = __expf(-sd);
    float Pn = 1.f;
#pragma unroll
    for (int n = 0; n < DSTATE; ++n) {
      Pn *= Qc;
      cP[base + n] = Pn; cS[base + n] = h[n];
    }
  } else {
    float P[DSTATE];
#pragma unroll
    for (int n = 0; n < DSTATE; ++n) P[n] = 1.f;
    for (int l = 0; l < CLEN; ++l) {
      const float dlt = b2f(Dsh[l * 256 + tid]);
      const float du = dlt * b2f(Ush[l * 256 + tid]);
#pragma unroll
      for (int n = 0; n < DSTATE; ++n) {
        const float dA = __expf(dlt * Av[n]);
        h[n] = fmaf(dA, h[n], du * Bsh[l][n]);
        P[n] *= dA;
      }
    }
#pragma unroll
    for (int n = 0; n < DSTATE; ++n) { cP[base + n] = P[n]; cS[base + n] = h[n]; }
  }
}

// ---------------------------------------------------------------------------
// Scan pass 2: sequential carry over chunks; ch0 may alias cP.
// ---------------------------------------------------------------------------
__global__ __launch_bounds__(256) void scan_pass2(
    const float* __restrict__ cP, const float* __restrict__ cS,
    float* __restrict__ ch0)
{
  const int dn = blockIdx.x * 256 + threadIdx.x;
  float h = 0.f;
  for (int c = 0; c < NCH; ++c) {
    const size_t o = (size_t)c * DI * DSTATE + dn;
    const float p = cP[o], s = cS[o];
    ch0[o] = h;
    h = fmaf(p, h, s);
  }
}

// ---------------------------------------------------------------------------
// Scan pass 3 (LDS-staged) + gate: y1b = bf16( (scan_y + u*D) * silu(res) ).
// ---------------------------------------------------------------------------
__global__ __launch_bounds__(256) void scan_pass3(
    const ushort_t* __restrict__ deltab, const ushort_t* __restrict__ xsb,
    const float* __restrict__ dblBC, const float* __restrict__ A_log,
    const float* __restrict__ ch0, const float* __restrict__ Dp,
    const ushort_t* __restrict__ xrb, ushort_t* __restrict__ y1b)
{
  const int tid = threadIdx.x;
  const int g = blockIdx.x;
  const int c = blockIdx.y;
  const int d = g * 256 + tid;
  __shared__ ushort_t Dsh[CLEN * 256];
  __shared__ ushort_t Ush[CLEN * 256];
  __shared__ float Bsh[CLEN][DSTATE];
  __shared__ float Csh[CLEN][DSTATE];

  const size_t rowbase = (size_t)(c * CLEN) * DI + g * 256;
  for (int i = tid; i < CLEN * 32; i += 256) {
    const int l = i >> 5;
    const int o = (i & 31) * 8;
    *(usx8*)&Dsh[l * 256 + o] = *(const usx8*)(deltab + rowbase + (size_t)l * DI + o);
    *(usx8*)&Ush[l * 256 + o] = *(const usx8*)(xsb   + rowbase + (size_t)l * DI + o);
  }
  for (int i = tid; i < CLEN * DSTATE; i += 256) {
    const int l = i >> 4, n = i & 15;
    const size_t row = (size_t)(c * CLEN + l) * 32;
    Bsh[l][n] = dblBC[row + n];
    Csh[l][n] = dblBC[row + 16 + n];
  }
  __syncthreads();

  float Av[DSTATE], h[DSTATE];
  const size_t base = (size_t)c * DI * DSTATE + (size_t)d * DSTATE;
#pragma unroll
  for (int n = 0; n < DSTATE; ++n) {
    Av[n] = -__expf(A_log[d * DSTATE + n]);
    h[n] = ch0[base + n];
  }
  const float Dd = Dp[d];
  const ushort_t* resp = xrb + (size_t)(c * CLEN) * (2 * DI) + DI + d;
  ushort_t* yp = y1b + (size_t)(c * CLEN) * DI + d;

  if (chain_ok(Av)) {
    for (int l = 0; l < CLEN; ++l) {
      const float dlt = b2f(Dsh[l * 256 + tid]);
      const float u = b2f(Ush[l * 256 + tid]);
      const float du = dlt * u;
      const float q = __expf(-dlt);
      float dAn = 1.f;
      float y = 0.f;
#pragma unroll
      for (int n = 0; n < DSTATE; ++n) {
        dAn *= q;
        h[n] = fmaf(dAn, h[n], du * Bsh[l][n]);
        y = fmaf(h[n], Csh[l][n], y);
      }
      y = fmaf(u, Dd, y);
      const float res = b2f(resp[(size_t)l * (2 * DI)]);
      yp[(size_t)l * DI] = f2b(y * siluf(res));
    }
  } else {
    for (int l = 0; l < CLEN; ++l) {
      const float dlt = b2f(Dsh[l * 256 + tid]);
      const float u = b2f(Ush[l * 256 + tid]);
      const float du = dlt * u;
      float y = 0.f;
#pragma unroll
      for (int n = 0; n < DSTATE; ++n) {
        const float dA = __expf(dlt * Av[n]);
        h[n] = fmaf(dA, h[n], du * Bsh[l][n]);
        y = fmaf(h[n], Csh[l][n], y);
      }
      y = fmaf(u, Dd, y);
      const float res = b2f(resp[(size_t)l * (2 * DI)]);
      yp[(size_t)l * DI] = f2b(y * siluf(res));
    }
  }
}

// ---------------------------------------------------------------------------
extern "C" void kernel_launch(void* const* d_in, const int* in_sizes, int n_in,
                              void* d_out, int out_size, void* d_ws, size_t ws_size,
                              hipStream_t stream) {
  (void)in_sizes; (void)n_in; (void)out_size; (void)ws_size;
  const float* x      = (const float*)d_in[0];
  const float* W_in   = (const float*)d_in[1];
  const float* conv_w = (const float*)d_in[2];
  const float* conv_b = (const float*)d_in[3];
  const float* W_x    = (const float*)d_in[4];
  const float* W_dt   = (const float*)d_in[5];
  const float* b_dt   = (const float*)d_in[6];
  const float* A_log  = (const float*)d_in[7];
  const float* Dp     = (const float*)d_in[8];
  const float* W_out  = (const float*)d_in[9];
  float* out = (float*)d_out;

  // workspace layout (r9 config).
  // partial (KSPLIT*L*96 f = 12.6 MB) aliases [cP, cS] (16.8 MB):
  //   gemm_dbl writes partial -> reduce_dbl consumes -> delta-GEMM ->
  //   scan_pass1 writes cP/cS. No live overlap.
  float* ws    = (float*)d_ws;
  float* cP    = ws;                                   // 2.1M f
  float* cS    = cP + (size_t)NCH * DI * DSTATE;       // 2.1M f
  ushort_t* deltab = (ushort_t*)(cS + (size_t)NCH * DI * DSTATE);  // L*DI bf16
  ushort_t* xrb   = deltab + (size_t)LSEQ * DI;        // L*2DI
  ushort_t* xsb   = xrb   + (size_t)LSEQ * 2 * DI;     // L*DI
  ushort_t* y1b   = xsb   + (size_t)LSEQ * DI;         // L*DI
  ushort_t* xb    = y1b   + (size_t)LSEQ * DI;         // L*DM
  ushort_t* W_inb = xb    + (size_t)LSEQ * DM;         // 2DI*DM
  ushort_t* W_outb= W_inb + (size_t)2 * DI * DM;       // DM*DI
  ushort_t* W_xb  = W_outb+ (size_t)DM * DI;           // 96*DI
  ushort_t* W_dtb = W_xb  + (size_t)DXW * DI;          // DI*64
  ushort_t* dtb   = W_dtb + (size_t)DI * DRNK;         // L*64
  float* dblBC = (float*)(dtb + (size_t)LSEQ * DRNK);  // L*32 f
  float* partial = cP;   // alias (see above)
  float* ch0 = cP;       // alias (in-place in scan_pass2)

  // 0) all input casts in one launch
  hipLaunchKernelGGL(cast_all, dim3((CTOT / 4 + 255) / 256), dim3(256), 0, stream,
                     x, W_in, W_out, W_x, W_dt, xb, W_inb, W_outb, W_xb, W_dtb);

  // 1) xrb = bf16(x @ W_in.T)  (M=4096, N=4096, K=1024), 32x32x16, BK=64
  hipLaunchKernelGGL(HIP_KERNEL_NAME(gemm32<1, 128>),
                     dim3((2 * DI) / 128, LSEQ / 128), dim3(256), 0, stream,
                     xb, DM, W_inb, DM, (void*)xrb, 2 * DI, DM);

  // 2) xsb = bf16(silu(conv(xi) + b)) — sliding window
  hipLaunchKernelGGL(conv2, dim3(LSEQ / 8), dim3(256), 0, stream,
                     xrb, conv_w, conv_b, xsb);

  // 3) partial[z] = xsb @ W_xb.T chunk z; then reduce -> dtb bf16 + dblBC f32
  hipLaunchKernelGGL(gemm_dbl, dim3(1, LSEQ / 128, KSPLIT), dim3(256), 0, stream,
                     xsb, W_xb, partial);
  hipLaunchKernelGGL(reduce_dbl, dim3((LSEQ * DXW) / 256), dim3(256), 0, stream,
                     partial, dtb, dblBC);

  // 4) deltab = bf16(softplus(dtb @ W_dtb.T + b_dt))  (K=64)
  hipLaunchKernelGGL(HIP_KERNEL_NAME(gemm_bf16<2, 128>),
                     dim3(DI / 128, LSEQ / 128), dim3(256), 0, stream,
                     dtb, DRNK, W_dtb, DRNK, (void*)deltab, DI, DRNK, b_dt);

  // 5) chunked selective scan (3-pass, CLEN=64 — validated optimum)
  hipLaunchKernelGGL(scan_pass1, dim3(DI / 256, NCH), dim3(256), 0, stream,
                     deltab, xsb, dblBC, A_log, cP, cS);
  hipLaunchKernelGGL(scan_pass2, dim3((DI * DSTATE) / 256), dim3(256), 0, stream,
                     cP, cS, ch0);
  hipLaunchKernelGGL(scan_pass3, dim3(DI / 256, NCH), dim3(256), 0, stream,
                     deltab, xsb, dblBC, A_log, ch0, Dp, xrb, y1b);

  // 6) out = y1b @ W_out.T  (M=4096, N=1024, K=2048), 32x32x16, BK=64
  hipLaunchKernelGGL(HIP_KERNEL_NAME(gemm32<0, 64>),
                     dim3(DM / 64, LSEQ / 128), dim3(256), 0, stream,
                     y1b, DI, W_outb, DI, (void*)out, DM, DI);
}

// Round 14
// 287.885 us; speedup vs baseline: 1.4503x; 1.0222x over previous
//
#include <hip/hip_runtime.h>
#include <cstdint>
#include <cstddef>

// Problem constants
#define LSEQ 4096
#define DM 1024
#define DI 2048
#define DCONV 4
#define DRNK 64
#define DSTATE 16
#define DXW 96        // DRNK + 2*DSTATE
#define NCH 64        // r11: CLEN=32/NCH=128 regressed — keep 64
#define CLEN 64       // LSEQ / NCH
#define KSPLIT 8      // split-K for dbl GEMM

typedef unsigned short ushort_t;
typedef __bf16 bfx8 __attribute__((ext_vector_type(8)));
typedef float  fx4  __attribute__((ext_vector_type(4)));
typedef float  fx16 __attribute__((ext_vector_type(16)));
typedef ushort_t usx8 __attribute__((ext_vector_type(8)));

__device__ __forceinline__ float siluf(float x) { return x / (1.f + __expf(-x)); }
__device__ __forceinline__ float softplusf(float x) {
  return fmaxf(x, 0.f) + log1pf(__expf(-fabsf(x)));
}
__device__ __forceinline__ ushort_t f2b(float x) {
  __bf16 b = (__bf16)x;   // RNE
  return __builtin_bit_cast(ushort_t, b);
}
__device__ __forceinline__ float b2f(ushort_t u) {
  unsigned int x = ((unsigned int)u) << 16;
  return __builtin_bit_cast(float, x);
}
__device__ __forceinline__ void async16(const void* g, void* l) {
  __builtin_amdgcn_global_load_lds(
      (const __attribute__((address_space(1))) unsigned int*)g,
      (__attribute__((address_space(3))) unsigned int*)l, 16, 0, 0);
}

// ---------------------------------------------------------------------------
// 32x32x16 bf16 MFMA NT GEMM, BK=64 (r13: halved barrier drain, 302->294us;
// r12: 32x32 frags beat 16x16 by ~8%). LDS row = 128B, 3-bit XOR swizzle
// (chunk ^ row&7). LDS 32KB (BN=128) / 24KB (BN=64).
// Wave-tile 64x(BN/2): MI=2 x NJ=BN/64 frags of 32x32.
// C/D: col=lane&31, row=(reg&3)+8*(reg>>2)+4*(lane>>5)  [m74/m101 verified].
// NOTE (r6): 128x256 tile regressed (occupancy). NOTE (r8/r10): scan fusion
// (cooperative or flag-synced) regressed ~3x — keep 3-pass scan.
// EPI: 0 = f32 store, 1 = bf16 store.
// ---------------------------------------------------------------------------
template <int EPI, int BN>
__global__ __launch_bounds__(256) void gemm32(
    const ushort_t* __restrict__ A, int lda,
    const ushort_t* __restrict__ B, int ldb,
    void* __restrict__ Cv, int ldc, int K)
{
  constexpr int MI = 2;
  constexpr int NJ = BN / 64;          // 2 (BN=128) or 1 (BN=64)
  __shared__ ushort_t As[128 * 64];
  __shared__ ushort_t Bs[BN * 64];
  const int tid  = threadIdx.x;
  const int m0   = blockIdx.y * 128, n0 = blockIdx.x * BN;
  const int lane = tid & 63;
  const int wave = tid >> 6;
  const int wm   = (wave >> 1) * 64, wn = (wave & 1) * (BN / 2);
  const int lm   = lane & 31;          // frag row
  const int kg   = lane >> 5;          // k-group (0/1)
  const int r0  = tid >> 3;
  const int pos = tid & 7;
  const int cswz = (pos ^ (r0 & 7)) * 8;
  const int key  = lm & 7;

  fx16 acc[MI][NJ] = {};

  const ushort_t* ga = A + (size_t)(m0 + r0) * lda + cswz;
  const ushort_t* gb = B + (size_t)(n0 + r0) * ldb + cswz;

  for (int k0 = 0; k0 < K; k0 += 64) {
#pragma unroll
    for (int t = 0; t < 4; ++t)
      async16(ga + (size_t)(32 * t) * lda + k0, &As[t * 32 * 64 + tid * 8]);
#pragma unroll
    for (int t = 0; t < BN / 32; ++t)
      async16(gb + (size_t)(32 * t) * ldb + k0, &Bs[t * 32 * 64 + tid * 8]);
    __syncthreads();

#pragma unroll
    for (int kk = 0; kk < 4; ++kk) {
      const int swz = ((kk * 2 + kg) ^ key) * 8;
      bfx8 af[MI], bfr[NJ];
#pragma unroll
      for (int i = 0; i < MI; ++i)
        af[i] = *(const bfx8*)&As[(wm + i * 32 + lm) * 64 + swz];
#pragma unroll
      for (int j = 0; j < NJ; ++j)
        bfr[j] = *(const bfx8*)&Bs[(wn + j * 32 + lm) * 64 + swz];
#pragma unroll
      for (int i = 0; i < MI; ++i)
#pragma unroll
        for (int j = 0; j < NJ; ++j)
          acc[i][j] = __builtin_amdgcn_mfma_f32_32x32x16_bf16(af[i], bfr[j], acc[i][j], 0, 0, 0);
    }
    __syncthreads();
  }

#pragma unroll
  for (int i = 0; i < MI; ++i)
#pragma unroll
    for (int j = 0; j < NJ; ++j)
#pragma unroll
      for (int r = 0; r < 16; ++r) {
        const int lrow = (r & 3) + 8 * (r >> 2) + 4 * kg;
        const size_t rowoff =
            (size_t)(m0 + wm + i * 32 + lrow) * ldc + n0 + wn + j * 32 + lm;
        if (EPI == 1) ((ushort_t*)Cv)[rowoff] = f2b(acc[i][j][r]);
        else          ((float*)Cv)[rowoff]   = acc[i][j][r];
      }
}

// ---------------------------------------------------------------------------
// Delta GEMM (r14): deltab[L,DI] bf16 = softplus(dtb[L,64] @ W_dtb[DI,64]^T
// + b_dt). K=64 = one BK=64 staging round: single barrier pair total.
// 32x32x16 frags, tile 128x128, grid (DI/128, L/128) = 512 blocks.
// ---------------------------------------------------------------------------
__global__ __launch_bounds__(256) void gemm_delta(
    const ushort_t* __restrict__ A,      // dtb, lda=64
    const ushort_t* __restrict__ B,      // W_dtb, ldb=64
    const float* __restrict__ bias,
    ushort_t* __restrict__ C)            // deltab, ldc=DI
{
  __shared__ ushort_t As[128 * 64];
  __shared__ ushort_t Bs[128 * 64];
  const int tid  = threadIdx.x;
  const int m0   = blockIdx.y * 128, n0 = blockIdx.x * 128;
  const int lane = tid & 63;
  const int wave = tid >> 6;
  const int wm   = (wave >> 1) * 64, wn = (wave & 1) * 64;
  const int lm   = lane & 31;
  const int kg   = lane >> 5;
  const int r0  = tid >> 3;
  const int pos = tid & 7;
  const int cswz = (pos ^ (r0 & 7)) * 8;
  const int key  = lm & 7;

  fx16 acc[2][2] = {};

#pragma unroll
  for (int t = 0; t < 4; ++t)
    async16(A + (size_t)(m0 + r0 + 32 * t) * DRNK + cswz, &As[t * 32 * 64 + tid * 8]);
#pragma unroll
  for (int t = 0; t < 4; ++t)
    async16(B + (size_t)(n0 + r0 + 32 * t) * DRNK + cswz, &Bs[t * 32 * 64 + tid * 8]);
  __syncthreads();

#pragma unroll
  for (int kk = 0; kk < 4; ++kk) {
    const int swz = ((kk * 2 + kg) ^ key) * 8;
    bfx8 af[2], bfr[2];
#pragma unroll
    for (int i = 0; i < 2; ++i)
      af[i] = *(const bfx8*)&As[(wm + i * 32 + lm) * 64 + swz];
#pragma unroll
    for (int j = 0; j < 2; ++j)
      bfr[j] = *(const bfx8*)&Bs[(wn + j * 32 + lm) * 64 + swz];
#pragma unroll
    for (int i = 0; i < 2; ++i)
#pragma unroll
      for (int j = 0; j < 2; ++j)
        acc[i][j] = __builtin_amdgcn_mfma_f32_32x32x16_bf16(af[i], bfr[j], acc[i][j], 0, 0, 0);
  }

#pragma unroll
  for (int i = 0; i < 2; ++i)
#pragma unroll
    for (int j = 0; j < 2; ++j) {
      const int col = n0 + wn + j * 32 + lm;
      const float bv = bias[col];
#pragma unroll
      for (int r = 0; r < 16; ++r) {
        const int lrow = (r & 3) + 8 * (r >> 2) + 4 * kg;
        C[(size_t)(m0 + wm + i * 32 + lrow) * DI + col] =
            f2b(softplusf(acc[i][j][r] + bv));
      }
    }
}

// ---------------------------------------------------------------------------
// dbl GEMM: partial[z][L,96] f32 = xsb bf16 @ W_xb bf16^T over K-chunk z.
// ---------------------------------------------------------------------------
__global__ __launch_bounds__(256) void gemm_dbl(
    const ushort_t* __restrict__ A, const ushort_t* __restrict__ B,
    float* __restrict__ P)
{
  __shared__ ushort_t As[128 * 32];
  __shared__ ushort_t Bs[128 * 32];
  const int tid  = threadIdx.x;
  const int m0   = blockIdx.y * 128;
  const int lane = tid & 63;
  const int wave = tid >> 6;
  const int wm   = (wave >> 1) * 64, wn = (wave & 1) * 48;
  const int lm   = lane & 15;
  const int r0 = tid >> 2;
  const int cswz = (((tid & 3) ^ ((r0 >> 1) & 3))) * 8;
  const int swz  = (((lane >> 4) ^ ((lm >> 1) & 3))) * 8;
  const int kbeg = blockIdx.z * (DI / KSPLIT);

  fx4 acc[4][3] = {};

  const int brow1 = (r0 + 64 < DXW) ? r0 + 64 : DXW - 1;  // clamp; rows>=96 unused
  const ushort_t* ga  = A + (size_t)(m0 + r0) * DI + kbeg + cswz;
  const ushort_t* gb0 = B + (size_t)r0 * DI + kbeg + cswz;
  const ushort_t* gb1 = B + (size_t)brow1 * DI + kbeg + cswz;
  ushort_t* la0 = &As[r0 * 32 + (tid & 3) * 8];
  ushort_t* la1 = &As[(r0 + 64) * 32 + (tid & 3) * 8];
  ushort_t* lb0 = &Bs[r0 * 32 + (tid & 3) * 8];
  ushort_t* lb1 = &Bs[(r0 + 64) * 32 + (tid & 3) * 8];

  for (int k0 = 0; k0 < DI / KSPLIT; k0 += 32) {
    async16(ga + k0, la0);
    async16(ga + (size_t)64 * DI + k0, la1);
    async16(gb0 + k0, lb0);
    async16(gb1 + k0, lb1);
    __syncthreads();

    bfx8 af[4], bfr[3];
#pragma unroll
    for (int i = 0; i < 4; ++i)
      af[i] = *(const bfx8*)&As[(wm + i * 16 + lm) * 32 + swz];
#pragma unroll
    for (int j = 0; j < 3; ++j)
      bfr[j] = *(const bfx8*)&Bs[(wn + j * 16 + lm) * 32 + swz];
#pragma unroll
    for (int i = 0; i < 4; ++i)
#pragma unroll
      for (int j = 0; j < 3; ++j)
        acc[i][j] = __builtin_amdgcn_mfma_f32_16x16x32_bf16(af[i], bfr[j], acc[i][j], 0, 0, 0);
    __syncthreads();
  }

  float* base = P + (size_t)blockIdx.z * LSEQ * DXW;
  const int crow = (lane >> 4) * 4;
  const int ccol = lane & 15;
#pragma unroll
  for (int i = 0; i < 4; ++i)
#pragma unroll
    for (int r = 0; r < 4; ++r) {
      float* cp = base + (size_t)(m0 + wm + i * 16 + crow + r) * DXW + wn + ccol;
#pragma unroll
      for (int j = 0; j < 3; ++j)
        cp[j * 16] = acc[i][j][r];
    }
}

// ---------------------------------------------------------------------------
// reduce_dbl: sum KSPLIT partials; emit dtb = bf16(cols 0..63) and
// dblBC = f32 compact (cols 64..95 -> [l][32]). Deterministic z-order.
// ---------------------------------------------------------------------------
__global__ __launch_bounds__(256) void reduce_dbl(
    const float* __restrict__ P, ushort_t* __restrict__ dtb,
    float* __restrict__ dblBC)
{
  const int f = blockIdx.x * 256 + threadIdx.x;     // < LSEQ*DXW
  float s = 0.f;
#pragma unroll
  for (int z = 0; z < KSPLIT; ++z) s += P[(size_t)z * LSEQ * DXW + f];
  const int l = f / DXW;
  const int c = f - l * DXW;
  if (c < DRNK) dtb[(size_t)l * DRNK + c] = f2b(s);
  else          dblBC[(size_t)l * 32 + (c - DRNK)] = s;
}

// ---------------------------------------------------------------------------
// Fused cast of all 5 constant inputs to bf16 (one launch).
// ---------------------------------------------------------------------------
#define CSZ0 (LSEQ * DM)        // x       4194304
#define CSZ1 (2 * DI * DM)      // W_in    4194304
#define CSZ2 (DM * DI)          // W_out   2097152
#define CSZ3 (DXW * DI)         // W_x      196608
#define CSZ4 (DI * DRNK)        // W_dt     131072
#define CTOT (CSZ0 + CSZ1 + CSZ2 + CSZ3 + CSZ4)

__global__ __launch_bounds__(256) void cast_all(
    const float* __restrict__ x, const float* __restrict__ W_in,
    const float* __restrict__ W_out, const float* __restrict__ W_x,
    const float* __restrict__ W_dt,
    ushort_t* __restrict__ xb, ushort_t* __restrict__ W_inb,
    ushort_t* __restrict__ W_outb, ushort_t* __restrict__ W_xb,
    ushort_t* __restrict__ W_dtb)
{
  int i = (blockIdx.x * 256 + threadIdx.x) * 4;
  if (i >= CTOT) return;
  const float* src; ushort_t* dst;
  if (i < CSZ0) { src = x + i; dst = xb + i; }
  else if (i < CSZ0 + CSZ1) { int o = i - CSZ0; src = W_in + o; dst = W_inb + o; }
  else if (i < CSZ0 + CSZ1 + CSZ2) { int o = i - CSZ0 - CSZ1; src = W_out + o; dst = W_outb + o; }
  else if (i < CSZ0 + CSZ1 + CSZ2 + CSZ3) { int o = i - CSZ0 - CSZ1 - CSZ2; src = W_x + o; dst = W_xb + o; }
  else { int o = i - CSZ0 - CSZ1 - CSZ2 - CSZ3; src = W_dt + o; dst = W_dtb + o; }
  float4 v = *(const float4*)src;
  ushort4 o4;
  o4.x = f2b(v.x); o4.y = f2b(v.y); o4.z = f2b(v.z); o4.w = f2b(v.w);
  *(ushort4*)dst = o4;
}

// ---------------------------------------------------------------------------
// Sliding-window depthwise causal conv (k=4) + bias + silu, bf16 in/out.
// ---------------------------------------------------------------------------
__global__ __launch_bounds__(256) void conv2(
    const ushort_t* __restrict__ xrb, const float* __restrict__ cw,
    const float* __restrict__ cb, ushort_t* __restrict__ xsb)
{
  const int d0 = threadIdx.x * 8;
  const int l0 = blockIdx.x * 8;

  float4 w[8];
#pragma unroll
  for (int j = 0; j < 8; ++j) w[j] = *(const float4*)(cw + (size_t)(d0 + j) * DCONV);
  float cbv[8];
  *(float4*)&cbv[0] = *(const float4*)(cb + d0);
  *(float4*)&cbv[4] = *(const float4*)(cb + d0 + 4);

  float h0[8], h1[8], h2[8];
#pragma unroll
  for (int j = 0; j < 8; ++j) { h0[j] = 0.f; h1[j] = 0.f; h2[j] = 0.f; }
  if (l0 >= 3) {
    usx8 u0 = *(const usx8*)(xrb + (size_t)(l0 - 3) * (2 * DI) + d0);
    usx8 u1 = *(const usx8*)(xrb + (size_t)(l0 - 2) * (2 * DI) + d0);
    usx8 u2 = *(const usx8*)(xrb + (size_t)(l0 - 1) * (2 * DI) + d0);
#pragma unroll
    for (int j = 0; j < 8; ++j) { h0[j] = b2f(u0[j]); h1[j] = b2f(u1[j]); h2[j] = b2f(u2[j]); }
  }

#pragma unroll
  for (int i = 0; i < 8; ++i) {
    const int l = l0 + i;
    usx8 uc = *(const usx8*)(xrb + (size_t)l * (2 * DI) + d0);
    float c[8];
#pragma unroll
    for (int j = 0; j < 8; ++j) c[j] = b2f(uc[j]);
    usx8 o;
#pragma unroll
    for (int j = 0; j < 8; ++j) {
      float acc = cbv[j];
      acc = fmaf(w[j].x, h0[j], acc);
      acc = fmaf(w[j].y, h1[j], acc);
      acc = fmaf(w[j].z, h2[j], acc);
      acc = fmaf(w[j].w, c[j], acc);
      o[j] = f2b(siluf(acc));
    }
    *(usx8*)(xsb + (size_t)l * DI + d0) = o;
#pragma unroll
    for (int j = 0; j < 8; ++j) { h0[j] = h1[j]; h1[j] = h2[j]; h2[j] = c[j]; }
  }
}

// ---------------------------------------------------------------------------
// Chain detector: S4D-real init gives Av[n] = -(n+1) exactly, so
// dA[n] = q^(n+1), q = exp(-dlt): 1 exp + 16 muls instead of 16 exps.
// ---------------------------------------------------------------------------
__device__ __forceinline__ bool chain_ok(const float* Av) {
  bool ok = true;
#pragma unroll
  for (int n = 0; n < DSTATE; ++n)
    ok = ok && (fabsf(Av[n] + (float)(n + 1)) < 1e-4f);
  return ok;
}

// ---------------------------------------------------------------------------
// Scan pass 1 (LDS-staged): local scan (h=0), emit sd = sum(dlt) and
// S = end state. r14: cP replaced by sd — P[n] = exp(Av[n]*sd) identically
// (product of exps collapses), so pass2 can reconstruct p from one scalar.
// Saves 8MB write here + 8MB read in pass2.
// ---------------------------------------------------------------------------
__global__ __launch_bounds__(256) void scan_pass1(
    const ushort_t* __restrict__ deltab, const ushort_t* __restrict__ xsb,
    const float* __restrict__ dblBC, const float* __restrict__ A_log,
    float* __restrict__ sd, float* __restrict__ cS)
{
  const int tid = threadIdx.x;
  const int g = blockIdx.x;            // dgroup (256 d's)
  const int c = blockIdx.y;            // chunk
  const int d = g * 256 + tid;
  __shared__ ushort_t Dsh[CLEN * 256];
  __shared__ ushort_t Ush[CLEN * 256];
  __shared__ float Bsh[CLEN][DSTATE];

  const size_t rowbase = (size_t)(c * CLEN) * DI + g * 256;
  for (int i = tid; i < CLEN * 32; i += 256) {
    const int l = i >> 5;
    const int o = (i & 31) * 8;
    *(usx8*)&Dsh[l * 256 + o] = *(const usx8*)(deltab + rowbase + (size_t)l * DI + o);
    *(usx8*)&Ush[l * 256 + o] = *(const usx8*)(xsb   + rowbase + (size_t)l * DI + o);
  }
  for (int i = tid; i < CLEN * DSTATE; i += 256) {
    const int l = i >> 4, n = i & 15;
    Bsh[l][n] = dblBC[(size_t)(c * CLEN + l) * 32 + n];
  }
  __syncthreads();

  float Av[DSTATE], h[DSTATE];
#pragma unroll
  for (int n = 0; n < DSTATE; ++n) {
    Av[n] = -__expf(A_log[d * DSTATE + n]);
    h[n] = 0.f;
  }
  const size_t base = (size_t)c * DI * DSTATE + (size_t)d * DSTATE;
  float sdv = 0.f;

  if (chain_ok(Av)) {
    for (int l = 0; l < CLEN; ++l) {
      const float dlt = b2f(Dsh[l * 256 + tid]);
      const float du = dlt * b2f(Ush[l * 256 + tid]);
      sdv += dlt;
      const float q = __expf(-dlt);
      float dAn = 1.f;
#pragma unroll
      for (int n = 0; n < DSTATE; ++n) {
        dAn *= q;
        h[n] = fmaf(dAn, h[n], du * Bsh[l][n]);
      }
    }
  } else {
    for (int l = 0; l < CLEN; ++l) {
      const float dlt = b2f(Dsh[l * 256 + tid]);
      const float du = dlt * b2f(Ush[l * 256 + tid]);
      sdv += dlt;
#pragma unroll
      for (int n = 0; n < DSTATE; ++n) {
        const float dA = __expf(dlt * Av[n]);
        h[n] = fmaf(dA, h[n], du * Bsh[l][n]);
      }
    }
  }
  sd[(size_t)c * DI + d] = sdv;
#pragma unroll
  for (int n = 0; n < DSTATE; ++n) cS[base + n] = h[n];
}

// ---------------------------------------------------------------------------
// Scan pass 2 (r14): sequential carry; p reconstructed as exp(av*sd).
// 64-thread blocks x 512 = all CUs engaged (was 128 blocks = half idle).
// ---------------------------------------------------------------------------
__global__ __launch_bounds__(64) void scan_pass2(
    const float* __restrict__ sd, const float* __restrict__ cS,
    const float* __restrict__ A_log, float* __restrict__ ch0)
{
  const int dn = blockIdx.x * 64 + threadIdx.x;   // 0..DI*DSTATE-1 = d*16+n
  const int d = dn >> 4;
  const float av = -__expf(A_log[dn]);            // A_log layout [d][n] == dn
  float h = 0.f;
  for (int c = 0; c < NCH; ++c) {
    const size_t o = (size_t)c * DI * DSTATE + dn;
    const float s = cS[o];
    const float p = __expf(av * sd[(size_t)c * DI + d]);
    ch0[o] = h;
    h = fmaf(p, h, s);
  }
}

// ---------------------------------------------------------------------------
// Scan pass 3 (LDS-staged) + gate: y1b = bf16( (scan_y + u*D) * silu(res) ).
// ---------------------------------------------------------------------------
__global__ __launch_bounds__(256) void scan_pass3(
    const ushort_t* __restrict__ deltab, const ushort_t* __restrict__ xsb,
    const float* __restrict__ dblBC, const float* __restrict__ A_log,
    const float* __restrict__ ch0, const float* __restrict__ Dp,
    const ushort_t* __restrict__ xrb, ushort_t* __restrict__ y1b)
{
  const int tid = threadIdx.x;
  const int g = blockIdx.x;
  const int c = blockIdx.y;
  const int d = g * 256 + tid;
  __shared__ ushort_t Dsh[CLEN * 256];
  __shared__ ushort_t Ush[CLEN * 256];
  __shared__ float Bsh[CLEN][DSTATE];
  __shared__ float Csh[CLEN][DSTATE];

  const size_t rowbase = (size_t)(c * CLEN) * DI + g * 256;
  for (int i = tid; i < CLEN * 32; i += 256) {
    const int l = i >> 5;
    const int o = (i & 31) * 8;
    *(usx8*)&Dsh[l * 256 + o] = *(const usx8*)(deltab + rowbase + (size_t)l * DI + o);
    *(usx8*)&Ush[l * 256 + o] = *(const usx8*)(xsb   + rowbase + (size_t)l * DI + o);
  }
  for (int i = tid; i < CLEN * DSTATE; i += 256) {
    const int l = i >> 4, n = i & 15;
    const size_t row = (size_t)(c * CLEN + l) * 32;
    Bsh[l][n] = dblBC[row + n];
    Csh[l][n] = dblBC[row + 16 + n];
  }
  __syncthreads();

  float Av[DSTATE], h[DSTATE];
  const size_t base = (size_t)c * DI * DSTATE + (size_t)d * DSTATE;
#pragma unroll
  for (int n = 0; n < DSTATE; ++n) {
    Av[n] = -__expf(A_log[d * DSTATE + n]);
    h[n] = ch0[base + n];
  }
  const float Dd = Dp[d];
  const ushort_t* resp = xrb + (size_t)(c * CLEN) * (2 * DI) + DI + d;
  ushort_t* yp = y1b + (size_t)(c * CLEN) * DI + d;

  if (chain_ok(Av)) {
    for (int l = 0; l < CLEN; ++l) {
      const float dlt = b2f(Dsh[l * 256 + tid]);
      const float u = b2f(Ush[l * 256 + tid]);
      const float du = dlt * u;
      const float q = __expf(-dlt);
      float dAn = 1.f;
      float y = 0.f;
#pragma unroll
      for (int n = 0; n < DSTATE; ++n) {
        dAn *= q;
        h[n] = fmaf(dAn, h[n], du * Bsh[l][n]);
        y = fmaf(h[n], Csh[l][n], y);
      }
      y = fmaf(u, Dd, y);
      const float res = b2f(resp[(size_t)l * (2 * DI)]);
      yp[(size_t)l * DI] = f2b(y * siluf(res));
    }
  } else {
    for (int l = 0; l < CLEN; ++l) {
      const float dlt = b2f(Dsh[l * 256 + tid]);
      const float u = b2f(Ush[l * 256 + tid]);
      const float du = dlt * u;
      float y = 0.f;
#pragma unroll
      for (int n = 0; n < DSTATE; ++n) {
        const float dA = __expf(dlt * Av[n]);
        h[n] = fmaf(dA, h[n], du * Bsh[l][n]);
        y = fmaf(h[n], Csh[l][n], y);
      }
      y = fmaf(u, Dd, y);
      const float res = b2f(resp[(size_t)l * (2 * DI)]);
      yp[(size_t)l * DI] = f2b(y * siluf(res));
    }
  }
}

// ---------------------------------------------------------------------------
extern "C" void kernel_launch(void* const* d_in, const int* in_sizes, int n_in,
                              void* d_out, int out_size, void* d_ws, size_t ws_size,
                              hipStream_t stream) {
  (void)in_sizes; (void)n_in; (void)out_size; (void)ws_size;
  const float* x      = (const float*)d_in[0];
  const float* W_in   = (const float*)d_in[1];
  const float* conv_w = (const float*)d_in[2];
  const float* conv_b = (const float*)d_in[3];
  const float* W_x    = (const float*)d_in[4];
  const float* W_dt   = (const float*)d_in[5];
  const float* b_dt   = (const float*)d_in[6];
  const float* A_log  = (const float*)d_in[7];
  const float* Dp     = (const float*)d_in[8];
  const float* W_out  = (const float*)d_in[9];
  float* out = (float*)d_out;

  // workspace layout.
  // partial (KSPLIT*L*96 f = 12.6 MB) aliases [sd, cS, ch0] (17.3 MB):
  //   gemm_dbl writes partial -> reduce_dbl consumes -> delta-GEMM ->
  //   scan_pass1 writes sd/cS -> pass2 writes ch0. No live overlap.
  float* ws    = (float*)d_ws;
  float* sd    = ws;                                   // NCH*DI f = 0.5 MB
  float* cS    = sd + (size_t)NCH * DI;                // NCH*DI*DSTATE f = 8.4 MB
  float* ch0   = cS + (size_t)NCH * DI * DSTATE;       // 8.4 MB
  ushort_t* deltab = (ushort_t*)(ch0 + (size_t)NCH * DI * DSTATE);  // L*DI bf16
  ushort_t* xrb   = deltab + (size_t)LSEQ * DI;        // L*2DI
  ushort_t* xsb   = xrb   + (size_t)LSEQ * 2 * DI;     // L*DI
  ushort_t* y1b   = xsb   + (size_t)LSEQ * DI;         // L*DI
  ushort_t* xb    = y1b   + (size_t)LSEQ * DI;         // L*DM
  ushort_t* W_inb = xb    + (size_t)LSEQ * DM;         // 2DI*DM
  ushort_t* W_outb= W_inb + (size_t)2 * DI * DM;       // DM*DI
  ushort_t* W_xb  = W_outb+ (size_t)DM * DI;           // 96*DI
  ushort_t* W_dtb = W_xb  + (size_t)DXW * DI;          // DI*64
  ushort_t* dtb   = W_dtb + (size_t)DI * DRNK;         // L*64
  float* dblBC = (float*)(dtb + (size_t)LSEQ * DRNK);  // L*32 f
  float* partial = ws;   // alias (see above)

  // 0) all input casts in one launch
  hipLaunchKernelGGL(cast_all, dim3((CTOT / 4 + 255) / 256), dim3(256), 0, stream,
                     x, W_in, W_out, W_x, W_dt, xb, W_inb, W_outb, W_xb, W_dtb);

  // 1) xrb = bf16(x @ W_in.T)  (M=4096, N=4096, K=1024), 32x32x16, BK=64
  hipLaunchKernelGGL(HIP_KERNEL_NAME(gemm32<1, 128>),
                     dim3((2 * DI) / 128, LSEQ / 128), dim3(256), 0, stream,
                     xb, DM, W_inb, DM, (void*)xrb, 2 * DI, DM);

  // 2) xsb = bf16(silu(conv(xi) + b)) — sliding window
  hipLaunchKernelGGL(conv2, dim3(LSEQ / 8), dim3(256), 0, stream,
                     xrb, conv_w, conv_b, xsb);

  // 3) partial[z] = xsb @ W_xb.T chunk z; then reduce -> dtb bf16 + dblBC f32
  hipLaunchKernelGGL(gemm_dbl, dim3(1, LSEQ / 128, KSPLIT), dim3(256), 0, stream,
                     xsb, W_xb, partial);
  hipLaunchKernelGGL(reduce_dbl, dim3((LSEQ * DXW) / 256), dim3(256), 0, stream,
                     partial, dtb, dblBC);

  // 4) deltab = bf16(softplus(dtb @ W_dtb.T + b_dt)) — K=64 single-iter 32x32
  hipLaunchKernelGGL(gemm_delta, dim3(DI / 128, LSEQ / 128), dim3(256), 0, stream,
                     dtb, W_dtb, b_dt, deltab);

  // 5) chunked selective scan (3-pass, CLEN=64; sd-compressed carry state)
  hipLaunchKernelGGL(scan_pass1, dim3(DI / 256, NCH), dim3(256), 0, stream,
                     deltab, xsb, dblBC, A_log, sd, cS);
  hipLaunchKernelGGL(scan_pass2, dim3((DI * DSTATE) / 64), dim3(64), 0, stream,
                     sd, cS, A_log, ch0);
  hipLaunchKernelGGL(scan_pass3, dim3(DI / 256, NCH), dim3(256), 0, stream,
                     deltab, xsb, dblBC, A_log, ch0, Dp, xrb, y1b);

  // 6) out = y1b @ W_out.T  (M=4096, N=1024, K=2048), 32x32x16, BK=64
  hipLaunchKernelGGL(HIP_KERNEL_NAME(gemm32<0, 64>),
                     dim3(DM / 64, LSEQ / 128), dim3(256), 0, stream,
                     y1b, DI, W_outb, DI, (void*)out, DM, DI);
}

// Round 15
// 279.873 us; speedup vs baseline: 1.4918x; 1.0286x over previous
//
#include <hip/hip_runtime.h>
#include <cstdint>
#include <cstddef>

// Problem constants
#define LSEQ 4096
#define DM 1024
#define DI 2048
#define DCONV 4
#define DRNK 64
#define DSTATE 16
#define DXW 96        // DRNK + 2*DSTATE
#define NCH 64        // r11: CLEN=32/NCH=128 regressed — keep 64
#define CLEN 64       // LSEQ / NCH
#define KSPLIT 8      // split-K for dbl GEMM

typedef unsigned short ushort_t;
typedef __bf16 bfx8 __attribute__((ext_vector_type(8)));
typedef float  fx4  __attribute__((ext_vector_type(4)));
typedef float  fx16 __attribute__((ext_vector_type(16)));
typedef ushort_t usx8 __attribute__((ext_vector_type(8)));

__device__ __forceinline__ float siluf(float x) { return x / (1.f + __expf(-x)); }
__device__ __forceinline__ float softplusf(float x) {
  return fmaxf(x, 0.f) + log1pf(__expf(-fabsf(x)));
}
__device__ __forceinline__ ushort_t f2b(float x) {
  __bf16 b = (__bf16)x;   // RNE
  return __builtin_bit_cast(ushort_t, b);
}
__device__ __forceinline__ float b2f(ushort_t u) {
  unsigned int x = ((unsigned int)u) << 16;
  return __builtin_bit_cast(float, x);
}
__device__ __forceinline__ void async16(const void* g, void* l) {
  __builtin_amdgcn_global_load_lds(
      (const __attribute__((address_space(1))) unsigned int*)g,
      (__attribute__((address_space(3))) unsigned int*)l, 16, 0, 0);
}

// ---------------------------------------------------------------------------
// GEMM-1 (r15): 256x128 tile, 512 threads (8 waves, wave-tile 64x64 = 2x2
// frags of 32x32), BK=64. Staged-bytes/FLOP 1.33x better than 128x128.
// NOT r6's failure: acc stays 64 VGPR/thread (r6 grew acc to 128 at 256thr).
// LDS 48KB -> 3 blocks/CU ceiling; grid 512 = 2/CU resident, 16 waves/CU.
// LDS row 128B, 3-bit XOR swizzle (chunk ^ row&7) on the global source;
// LDS dest stays lane-linear (tid*16B) as global_load_lds requires.
// C/D: col=lane&31, row=(reg&3)+8*(reg>>2)+4*(lane>>5)  [m74/m101 verified].
// bf16 store epilogue. M%256==0, N%128==0, K%64==0.
// ---------------------------------------------------------------------------
__global__ __launch_bounds__(512) void gemm_wide(
    const ushort_t* __restrict__ A, int lda,
    const ushort_t* __restrict__ B, int ldb,
    ushort_t* __restrict__ C, int ldc, int K)
{
  __shared__ ushort_t As[256 * 64];
  __shared__ ushort_t Bs[128 * 64];
  const int tid  = threadIdx.x;
  const int m0   = blockIdx.y * 256, n0 = blockIdx.x * 128;
  const int lane = tid & 63;
  const int wave = tid >> 6;           // 0..7
  const int wm   = (wave >> 1) * 64;   // 0,64,128,192
  const int wn   = (wave & 1) * 64;    // 0,64
  const int lm   = lane & 31;
  const int kg   = lane >> 5;
  const int r0  = tid >> 3;            // 0..63 rows per issue
  const int pos = tid & 7;
  const int cswz = (pos ^ (r0 & 7)) * 8;
  const int key  = lm & 7;

  fx16 acc[2][2] = {};

  const ushort_t* ga = A + (size_t)(m0 + r0) * lda + cswz;
  const ushort_t* gb = B + (size_t)(n0 + r0) * ldb + cswz;

  for (int k0 = 0; k0 < K; k0 += 64) {
#pragma unroll
    for (int t = 0; t < 4; ++t)
      async16(ga + (size_t)(64 * t) * lda + k0, &As[t * 64 * 64 + tid * 8]);
#pragma unroll
    for (int t = 0; t < 2; ++t)
      async16(gb + (size_t)(64 * t) * ldb + k0, &Bs[t * 64 * 64 + tid * 8]);
    __syncthreads();

#pragma unroll
    for (int kk = 0; kk < 4; ++kk) {
      const int swz = ((kk * 2 + kg) ^ key) * 8;
      bfx8 af[2], bfr[2];
#pragma unroll
      for (int i = 0; i < 2; ++i)
        af[i] = *(const bfx8*)&As[(wm + i * 32 + lm) * 64 + swz];
#pragma unroll
      for (int j = 0; j < 2; ++j)
        bfr[j] = *(const bfx8*)&Bs[(wn + j * 32 + lm) * 64 + swz];
#pragma unroll
      for (int i = 0; i < 2; ++i)
#pragma unroll
        for (int j = 0; j < 2; ++j)
          acc[i][j] = __builtin_amdgcn_mfma_f32_32x32x16_bf16(af[i], bfr[j], acc[i][j], 0, 0, 0);
    }
    __syncthreads();
  }

#pragma unroll
  for (int i = 0; i < 2; ++i)
#pragma unroll
    for (int j = 0; j < 2; ++j)
#pragma unroll
      for (int r = 0; r < 16; ++r) {
        const int lrow = (r & 3) + 8 * (r >> 2) + 4 * kg;
        C[(size_t)(m0 + wm + i * 32 + lrow) * ldc + n0 + wn + j * 32 + lm] =
            f2b(acc[i][j][r]);
      }
}

// ---------------------------------------------------------------------------
// 32x32x16 bf16 MFMA NT GEMM, BK=64, 128xBN tile, 256 thr (r12/r13 lineage;
// used for GEMM-3). NOTE (r8/r10): scan fusion regressed ~3x — keep 3-pass.
// EPI: 0 = f32 store, 1 = bf16 store.
// ---------------------------------------------------------------------------
template <int EPI, int BN>
__global__ __launch_bounds__(256) void gemm32(
    const ushort_t* __restrict__ A, int lda,
    const ushort_t* __restrict__ B, int ldb,
    void* __restrict__ Cv, int ldc, int K)
{
  constexpr int MI = 2;
  constexpr int NJ = BN / 64;          // 2 (BN=128) or 1 (BN=64)
  __shared__ ushort_t As[128 * 64];
  __shared__ ushort_t Bs[BN * 64];
  const int tid  = threadIdx.x;
  const int m0   = blockIdx.y * 128, n0 = blockIdx.x * BN;
  const int lane = tid & 63;
  const int wave = tid >> 6;
  const int wm   = (wave >> 1) * 64, wn = (wave & 1) * (BN / 2);
  const int lm   = lane & 31;
  const int kg   = lane >> 5;
  const int r0  = tid >> 3;
  const int pos = tid & 7;
  const int cswz = (pos ^ (r0 & 7)) * 8;
  const int key  = lm & 7;

  fx16 acc[MI][NJ] = {};

  const ushort_t* ga = A + (size_t)(m0 + r0) * lda + cswz;
  const ushort_t* gb = B + (size_t)(n0 + r0) * ldb + cswz;

  for (int k0 = 0; k0 < K; k0 += 64) {
#pragma unroll
    for (int t = 0; t < 4; ++t)
      async16(ga + (size_t)(32 * t) * lda + k0, &As[t * 32 * 64 + tid * 8]);
#pragma unroll
    for (int t = 0; t < BN / 32; ++t)
      async16(gb + (size_t)(32 * t) * ldb + k0, &Bs[t * 32 * 64 + tid * 8]);
    __syncthreads();

#pragma unroll
    for (int kk = 0; kk < 4; ++kk) {
      const int swz = ((kk * 2 + kg) ^ key) * 8;
      bfx8 af[MI], bfr[NJ];
#pragma unroll
      for (int i = 0; i < MI; ++i)
        af[i] = *(const bfx8*)&As[(wm + i * 32 + lm) * 64 + swz];
#pragma unroll
      for (int j = 0; j < NJ; ++j)
        bfr[j] = *(const bfx8*)&Bs[(wn + j * 32 + lm) * 64 + swz];
#pragma unroll
      for (int i = 0; i < MI; ++i)
#pragma unroll
        for (int j = 0; j < NJ; ++j)
          acc[i][j] = __builtin_amdgcn_mfma_f32_32x32x16_bf16(af[i], bfr[j], acc[i][j], 0, 0, 0);
    }
    __syncthreads();
  }

#pragma unroll
  for (int i = 0; i < MI; ++i)
#pragma unroll
    for (int j = 0; j < NJ; ++j)
#pragma unroll
      for (int r = 0; r < 16; ++r) {
        const int lrow = (r & 3) + 8 * (r >> 2) + 4 * kg;
        const size_t rowoff =
            (size_t)(m0 + wm + i * 32 + lrow) * ldc + n0 + wn + j * 32 + lm;
        if (EPI == 1) ((ushort_t*)Cv)[rowoff] = f2b(acc[i][j][r]);
        else          ((float*)Cv)[rowoff]   = acc[i][j][r];
      }
}

// ---------------------------------------------------------------------------
// Delta GEMM (r14): deltab = bf16(softplus(dtb @ W_dtb^T + b_dt)). K=64 =
// one BK=64 staging round, single barrier pair. 32x32 frags, tile 128x128.
// ---------------------------------------------------------------------------
__global__ __launch_bounds__(256) void gemm_delta(
    const ushort_t* __restrict__ A,      // dtb, lda=64
    const ushort_t* __restrict__ B,      // W_dtb, ldb=64
    const float* __restrict__ bias,
    ushort_t* __restrict__ C)            // deltab, ldc=DI
{
  __shared__ ushort_t As[128 * 64];
  __shared__ ushort_t Bs[128 * 64];
  const int tid  = threadIdx.x;
  const int m0   = blockIdx.y * 128, n0 = blockIdx.x * 128;
  const int lane = tid & 63;
  const int wave = tid >> 6;
  const int wm   = (wave >> 1) * 64, wn = (wave & 1) * 64;
  const int lm   = lane & 31;
  const int kg   = lane >> 5;
  const int r0  = tid >> 3;
  const int pos = tid & 7;
  const int cswz = (pos ^ (r0 & 7)) * 8;
  const int key  = lm & 7;

  fx16 acc[2][2] = {};

#pragma unroll
  for (int t = 0; t < 4; ++t)
    async16(A + (size_t)(m0 + r0 + 32 * t) * DRNK + cswz, &As[t * 32 * 64 + tid * 8]);
#pragma unroll
  for (int t = 0; t < 4; ++t)
    async16(B + (size_t)(n0 + r0 + 32 * t) * DRNK + cswz, &Bs[t * 32 * 64 + tid * 8]);
  __syncthreads();

#pragma unroll
  for (int kk = 0; kk < 4; ++kk) {
    const int swz = ((kk * 2 + kg) ^ key) * 8;
    bfx8 af[2], bfr[2];
#pragma unroll
    for (int i = 0; i < 2; ++i)
      af[i] = *(const bfx8*)&As[(wm + i * 32 + lm) * 64 + swz];
#pragma unroll
    for (int j = 0; j < 2; ++j)
      bfr[j] = *(const bfx8*)&Bs[(wn + j * 32 + lm) * 64 + swz];
#pragma unroll
    for (int i = 0; i < 2; ++i)
#pragma unroll
      for (int j = 0; j < 2; ++j)
        acc[i][j] = __builtin_amdgcn_mfma_f32_32x32x16_bf16(af[i], bfr[j], acc[i][j], 0, 0, 0);
  }

#pragma unroll
  for (int i = 0; i < 2; ++i)
#pragma unroll
    for (int j = 0; j < 2; ++j) {
      const int col = n0 + wn + j * 32 + lm;
      const float bv = bias[col];
#pragma unroll
      for (int r = 0; r < 16; ++r) {
        const int lrow = (r & 3) + 8 * (r >> 2) + 4 * kg;
        C[(size_t)(m0 + wm + i * 32 + lrow) * DI + col] =
            f2b(softplusf(acc[i][j][r] + bv));
      }
    }
}

// ---------------------------------------------------------------------------
// dbl GEMM (r15): 32x32 frags, BK=64. Tile 128(M)x96(N); 4 waves, wave-tile
// 32x96 (MI=1, NJ=3). partial[z][L,96] f32, plain stores.
// K-chunk per z = DI/KSPLIT = 256 -> 4 iters.
// ---------------------------------------------------------------------------
__global__ __launch_bounds__(256) void gemm_dbl(
    const ushort_t* __restrict__ A, const ushort_t* __restrict__ B,
    float* __restrict__ P)
{
  __shared__ ushort_t As[128 * 64];
  __shared__ ushort_t Bs[96 * 64];
  const int tid  = threadIdx.x;
  const int m0   = blockIdx.y * 128;
  const int lane = tid & 63;
  const int wave = tid >> 6;
  const int wm   = wave * 32;          // 0,32,64,96
  const int lm   = lane & 31;
  const int kg   = lane >> 5;
  const int r0  = tid >> 3;            // 0..31 rows per issue
  const int pos = tid & 7;
  const int cswz = (pos ^ (r0 & 7)) * 8;
  const int key  = lm & 7;
  const int kbeg = blockIdx.z * (DI / KSPLIT);

  fx16 acc[3] = {};

  const ushort_t* ga = A + (size_t)(m0 + r0) * DI + kbeg + cswz;
  const ushort_t* gb = B + (size_t)r0 * DI + kbeg + cswz;

  for (int k0 = 0; k0 < DI / KSPLIT; k0 += 64) {
#pragma unroll
    for (int t = 0; t < 4; ++t)
      async16(ga + (size_t)(32 * t) * DI + k0, &As[t * 32 * 64 + tid * 8]);
#pragma unroll
    for (int t = 0; t < 3; ++t)
      async16(gb + (size_t)(32 * t) * DI + k0, &Bs[t * 32 * 64 + tid * 8]);
    __syncthreads();

#pragma unroll
    for (int kk = 0; kk < 4; ++kk) {
      const int swz = ((kk * 2 + kg) ^ key) * 8;
      bfx8 af = *(const bfx8*)&As[(wm + lm) * 64 + swz];
      bfx8 bfr[3];
#pragma unroll
      for (int j = 0; j < 3; ++j)
        bfr[j] = *(const bfx8*)&Bs[(j * 32 + lm) * 64 + swz];
#pragma unroll
      for (int j = 0; j < 3; ++j)
        acc[j] = __builtin_amdgcn_mfma_f32_32x32x16_bf16(af, bfr[j], acc[j], 0, 0, 0);
    }
    __syncthreads();
  }

  float* base = P + (size_t)blockIdx.z * LSEQ * DXW;
#pragma unroll
  for (int j = 0; j < 3; ++j)
#pragma unroll
    for (int r = 0; r < 16; ++r) {
      const int lrow = (r & 3) + 8 * (r >> 2) + 4 * kg;
      base[(size_t)(m0 + wm + lrow) * DXW + j * 32 + lm] = acc[j][r];
    }
}

// ---------------------------------------------------------------------------
// reduce_dbl: sum KSPLIT partials; emit dtb = bf16(cols 0..63) and
// dblBC = f32 compact (cols 64..95 -> [l][32]). Deterministic z-order.
// ---------------------------------------------------------------------------
__global__ __launch_bounds__(256) void reduce_dbl(
    const float* __restrict__ P, ushort_t* __restrict__ dtb,
    float* __restrict__ dblBC)
{
  const int f = blockIdx.x * 256 + threadIdx.x;     // < LSEQ*DXW
  float s = 0.f;
#pragma unroll
  for (int z = 0; z < KSPLIT; ++z) s += P[(size_t)z * LSEQ * DXW + f];
  const int l = f / DXW;
  const int c = f - l * DXW;
  if (c < DRNK) dtb[(size_t)l * DRNK + c] = f2b(s);
  else          dblBC[(size_t)l * 32 + (c - DRNK)] = s;
}

// ---------------------------------------------------------------------------
// Fused cast of all 5 constant inputs to bf16 (one launch).
// ---------------------------------------------------------------------------
#define CSZ0 (LSEQ * DM)        // x       4194304
#define CSZ1 (2 * DI * DM)      // W_in    4194304
#define CSZ2 (DM * DI)          // W_out   2097152
#define CSZ3 (DXW * DI)         // W_x      196608
#define CSZ4 (DI * DRNK)        // W_dt     131072
#define CTOT (CSZ0 + CSZ1 + CSZ2 + CSZ3 + CSZ4)

__global__ __launch_bounds__(256) void cast_all(
    const float* __restrict__ x, const float* __restrict__ W_in,
    const float* __restrict__ W_out, const float* __restrict__ W_x,
    const float* __restrict__ W_dt,
    ushort_t* __restrict__ xb, ushort_t* __restrict__ W_inb,
    ushort_t* __restrict__ W_outb, ushort_t* __restrict__ W_xb,
    ushort_t* __restrict__ W_dtb)
{
  int i = (blockIdx.x * 256 + threadIdx.x) * 4;
  if (i >= CTOT) return;
  const float* src; ushort_t* dst;
  if (i < CSZ0) { src = x + i; dst = xb + i; }
  else if (i < CSZ0 + CSZ1) { int o = i - CSZ0; src = W_in + o; dst = W_inb + o; }
  else if (i < CSZ0 + CSZ1 + CSZ2) { int o = i - CSZ0 - CSZ1; src = W_out + o; dst = W_outb + o; }
  else if (i < CSZ0 + CSZ1 + CSZ2 + CSZ3) { int o = i - CSZ0 - CSZ1 - CSZ2; src = W_x + o; dst = W_xb + o; }
  else { int o = i - CSZ0 - CSZ1 - CSZ2 - CSZ3; src = W_dt + o; dst = W_dtb + o; }
  float4 v = *(const float4*)src;
  ushort4 o4;
  o4.x = f2b(v.x); o4.y = f2b(v.y); o4.z = f2b(v.z); o4.w = f2b(v.w);
  *(ushort4*)dst = o4;
}

// ---------------------------------------------------------------------------
// Sliding-window depthwise causal conv (k=4) + bias + silu, bf16 in/out.
// ---------------------------------------------------------------------------
__global__ __launch_bounds__(256) void conv2(
    const ushort_t* __restrict__ xrb, const float* __restrict__ cw,
    const float* __restrict__ cb, ushort_t* __restrict__ xsb)
{
  const int d0 = threadIdx.x * 8;
  const int l0 = blockIdx.x * 8;

  float4 w[8];
#pragma unroll
  for (int j = 0; j < 8; ++j) w[j] = *(const float4*)(cw + (size_t)(d0 + j) * DCONV);
  float cbv[8];
  *(float4*)&cbv[0] = *(const float4*)(cb + d0);
  *(float4*)&cbv[4] = *(const float4*)(cb + d0 + 4);

  float h0[8], h1[8], h2[8];
#pragma unroll
  for (int j = 0; j < 8; ++j) { h0[j] = 0.f; h1[j] = 0.f; h2[j] = 0.f; }
  if (l0 >= 3) {
    usx8 u0 = *(const usx8*)(xrb + (size_t)(l0 - 3) * (2 * DI) + d0);
    usx8 u1 = *(const usx8*)(xrb + (size_t)(l0 - 2) * (2 * DI) + d0);
    usx8 u2 = *(const usx8*)(xrb + (size_t)(l0 - 1) * (2 * DI) + d0);
#pragma unroll
    for (int j = 0; j < 8; ++j) { h0[j] = b2f(u0[j]); h1[j] = b2f(u1[j]); h2[j] = b2f(u2[j]); }
  }

#pragma unroll
  for (int i = 0; i < 8; ++i) {
    const int l = l0 + i;
    usx8 uc = *(const usx8*)(xrb + (size_t)l * (2 * DI) + d0);
    float c[8];
#pragma unroll
    for (int j = 0; j < 8; ++j) c[j] = b2f(uc[j]);
    usx8 o;
#pragma unroll
    for (int j = 0; j < 8; ++j) {
      float acc = cbv[j];
      acc = fmaf(w[j].x, h0[j], acc);
      acc = fmaf(w[j].y, h1[j], acc);
      acc = fmaf(w[j].z, h2[j], acc);
      acc = fmaf(w[j].w, c[j], acc);
      o[j] = f2b(siluf(acc));
    }
    *(usx8*)(xsb + (size_t)l * DI + d0) = o;
#pragma unroll
    for (int j = 0; j < 8; ++j) { h0[j] = h1[j]; h1[j] = h2[j]; h2[j] = c[j]; }
  }
}

// ---------------------------------------------------------------------------
// Chain detector: S4D-real init gives Av[n] = -(n+1) exactly, so
// dA[n] = q^(n+1), q = exp(-dlt): 1 exp + 16 muls instead of 16 exps.
// ---------------------------------------------------------------------------
__device__ __forceinline__ bool chain_ok(const float* Av) {
  bool ok = true;
#pragma unroll
  for (int n = 0; n < DSTATE; ++n)
    ok = ok && (fabsf(Av[n] + (float)(n + 1)) < 1e-4f);
  return ok;
}

// ---------------------------------------------------------------------------
// Scan pass 1 (LDS-staged): local scan (h=0), emit sd = sum(dlt) and
// S = end state (r14: cP compressed to sd since P[n] = exp(Av[n]*sd)).
// ---------------------------------------------------------------------------
__global__ __launch_bounds__(256) void scan_pass1(
    const ushort_t* __restrict__ deltab, const ushort_t* __restrict__ xsb,
    const float* __restrict__ dblBC, const float* __restrict__ A_log,
    float* __restrict__ sd, float* __restrict__ cS)
{
  const int tid = threadIdx.x;
  const int g = blockIdx.x;            // dgroup (256 d's)
  const int c = blockIdx.y;            // chunk
  const int d = g * 256 + tid;
  __shared__ ushort_t Dsh[CLEN * 256];
  __shared__ ushort_t Ush[CLEN * 256];
  __shared__ float Bsh[CLEN][DSTATE];

  const size_t rowbase = (size_t)(c * CLEN) * DI + g * 256;
  for (int i = tid; i < CLEN * 32; i += 256) {
    const int l = i >> 5;
    const int o = (i & 31) * 8;
    *(usx8*)&Dsh[l * 256 + o] = *(const usx8*)(deltab + rowbase + (size_t)l * DI + o);
    *(usx8*)&Ush[l * 256 + o] = *(const usx8*)(xsb   + rowbase + (size_t)l * DI + o);
  }
  for (int i = tid; i < CLEN * DSTATE; i += 256) {
    const int l = i >> 4, n = i & 15;
    Bsh[l][n] = dblBC[(size_t)(c * CLEN + l) * 32 + n];
  }
  __syncthreads();

  float Av[DSTATE], h[DSTATE];
#pragma unroll
  for (int n = 0; n < DSTATE; ++n) {
    Av[n] = -__expf(A_log[d * DSTATE + n]);
    h[n] = 0.f;
  }
  const size_t base = (size_t)c * DI * DSTATE + (size_t)d * DSTATE;
  float sdv = 0.f;

  if (chain_ok(Av)) {
    for (int l = 0; l < CLEN; ++l) {
      const float dlt = b2f(Dsh[l * 256 + tid]);
      const float du = dlt * b2f(Ush[l * 256 + tid]);
      sdv += dlt;
      const float q = __expf(-dlt);
      float dAn = 1.f;
#pragma unroll
      for (int n = 0; n < DSTATE; ++n) {
        dAn *= q;
        h[n] = fmaf(dAn, h[n], du * Bsh[l][n]);
      }
    }
  } else {
    for (int l = 0; l < CLEN; ++l) {
      const float dlt = b2f(Dsh[l * 256 + tid]);
      const float du = dlt * b2f(Ush[l * 256 + tid]);
      sdv += dlt;
#pragma unroll
      for (int n = 0; n < DSTATE; ++n) {
        const float dA = __expf(dlt * Av[n]);
        h[n] = fmaf(dA, h[n], du * Bsh[l][n]);
      }
    }
  }
  sd[(size_t)c * DI + d] = sdv;
#pragma unroll
  for (int n = 0; n < DSTATE; ++n) cS[base + n] = h[n];
}

// ---------------------------------------------------------------------------
// Scan pass 2: sequential carry; p reconstructed as exp(av*sd).
// 64-thread blocks x 512 = all CUs engaged.
// ---------------------------------------------------------------------------
__global__ __launch_bounds__(64) void scan_pass2(
    const float* __restrict__ sd, const float* __restrict__ cS,
    const float* __restrict__ A_log, float* __restrict__ ch0)
{
  const int dn = blockIdx.x * 64 + threadIdx.x;   // d*16+n
  const int d = dn >> 4;
  const float av = -__expf(A_log[dn]);
  float h = 0.f;
  for (int c = 0; c < NCH; ++c) {
    const size_t o = (size_t)c * DI * DSTATE + dn;
    const float s = cS[o];
    const float p = __expf(av * sd[(size_t)c * DI + d]);
    ch0[o] = h;
    h = fmaf(p, h, s);
  }
}

// ---------------------------------------------------------------------------
// Scan pass 3 (LDS-staged) + gate: y1b = bf16( (scan_y + u*D) * silu(res) ).
// ---------------------------------------------------------------------------
__global__ __launch_bounds__(256) void scan_pass3(
    const ushort_t* __restrict__ deltab, const ushort_t* __restrict__ xsb,
    const float* __restrict__ dblBC, const float* __restrict__ A_log,
    const float* __restrict__ ch0, const float* __restrict__ Dp,
    const ushort_t* __restrict__ xrb, ushort_t* __restrict__ y1b)
{
  const int tid = threadIdx.x;
  const int g = blockIdx.x;
  const int c = blockIdx.y;
  const int d = g * 256 + tid;
  __shared__ ushort_t Dsh[CLEN * 256];
  __shared__ ushort_t Ush[CLEN * 256];
  __shared__ float Bsh[CLEN][DSTATE];
  __shared__ float Csh[CLEN][DSTATE];

  const size_t rowbase = (size_t)(c * CLEN) * DI + g * 256;
  for (int i = tid; i < CLEN * 32; i += 256) {
    const int l = i >> 5;
    const int o = (i & 31) * 8;
    *(usx8*)&Dsh[l * 256 + o] = *(const usx8*)(deltab + rowbase + (size_t)l * DI + o);
    *(usx8*)&Ush[l * 256 + o] = *(const usx8*)(xsb   + rowbase + (size_t)l * DI + o);
  }
  for (int i = tid; i < CLEN * DSTATE; i += 256) {
    const int l = i >> 4, n = i & 15;
    const size_t row = (size_t)(c * CLEN + l) * 32;
    Bsh[l][n] = dblBC[row + n];
    Csh[l][n] = dblBC[row + 16 + n];
  }
  __syncthreads();

  float Av[DSTATE], h[DSTATE];
  const size_t base = (size_t)c * DI * DSTATE + (size_t)d * DSTATE;
#pragma unroll
  for (int n = 0; n < DSTATE; ++n) {
    Av[n] = -__expf(A_log[d * DSTATE + n]);
    h[n] = ch0[base + n];
  }
  const float Dd = Dp[d];
  const ushort_t* resp = xrb + (size_t)(c * CLEN) * (2 * DI) + DI + d;
  ushort_t* yp = y1b + (size_t)(c * CLEN) * DI + d;

  if (chain_ok(Av)) {
    for (int l = 0; l < CLEN; ++l) {
      const float dlt = b2f(Dsh[l * 256 + tid]);
      const float u = b2f(Ush[l * 256 + tid]);
      const float du = dlt * u;
      const float q = __expf(-dlt);
      float dAn = 1.f;
      float y = 0.f;
#pragma unroll
      for (int n = 0; n < DSTATE; ++n) {
        dAn *= q;
        h[n] = fmaf(dAn, h[n], du * Bsh[l][n]);
        y = fmaf(h[n], Csh[l][n], y);
      }
      y = fmaf(u, Dd, y);
      const float res = b2f(resp[(size_t)l * (2 * DI)]);
      yp[(size_t)l * DI] = f2b(y * siluf(res));
    }
  } else {
    for (int l = 0; l < CLEN; ++l) {
      const float dlt = b2f(Dsh[l * 256 + tid]);
      const float u = b2f(Ush[l * 256 + tid]);
      const float du = dlt * u;
      float y = 0.f;
#pragma unroll
      for (int n = 0; n < DSTATE; ++n) {
        const float dA = __expf(dlt * Av[n]);
        h[n] = fmaf(dA, h[n], du * Bsh[l][n]);
        y = fmaf(h[n], Csh[l][n], y);
      }
      y = fmaf(u, Dd, y);
      const float res = b2f(resp[(size_t)l * (2 * DI)]);
      yp[(size_t)l * DI] = f2b(y * siluf(res));
    }
  }
}

// ---------------------------------------------------------------------------
extern "C" void kernel_launch(void* const* d_in, const int* in_sizes, int n_in,
                              void* d_out, int out_size, void* d_ws, size_t ws_size,
                              hipStream_t stream) {
  (void)in_sizes; (void)n_in; (void)out_size; (void)ws_size;
  const float* x      = (const float*)d_in[0];
  const float* W_in   = (const float*)d_in[1];
  const float* conv_w = (const float*)d_in[2];
  const float* conv_b = (const float*)d_in[3];
  const float* W_x    = (const float*)d_in[4];
  const float* W_dt   = (const float*)d_in[5];
  const float* b_dt   = (const float*)d_in[6];
  const float* A_log  = (const float*)d_in[7];
  const float* Dp     = (const float*)d_in[8];
  const float* W_out  = (const float*)d_in[9];
  float* out = (float*)d_out;

  // workspace layout.
  // partial (KSPLIT*L*96 f = 12.6 MB) aliases [sd, cS, ch0] (17.3 MB):
  //   gemm_dbl writes partial -> reduce_dbl consumes -> delta-GEMM ->
  //   scan_pass1 writes sd/cS -> pass2 writes ch0. No live overlap.
  float* ws    = (float*)d_ws;
  float* sd    = ws;                                   // NCH*DI f = 0.5 MB
  float* cS    = sd + (size_t)NCH * DI;                // 8.4 MB
  float* ch0   = cS + (size_t)NCH * DI * DSTATE;       // 8.4 MB
  ushort_t* deltab = (ushort_t*)(ch0 + (size_t)NCH * DI * DSTATE);  // L*DI bf16
  ushort_t* xrb   = deltab + (size_t)LSEQ * DI;        // L*2DI
  ushort_t* xsb   = xrb   + (size_t)LSEQ * 2 * DI;     // L*DI
  ushort_t* y1b   = xsb   + (size_t)LSEQ * DI;         // L*DI
  ushort_t* xb    = y1b   + (size_t)LSEQ * DI;         // L*DM
  ushort_t* W_inb = xb    + (size_t)LSEQ * DM;         // 2DI*DM
  ushort_t* W_outb= W_inb + (size_t)2 * DI * DM;       // DM*DI
  ushort_t* W_xb  = W_outb+ (size_t)DM * DI;           // 96*DI
  ushort_t* W_dtb = W_xb  + (size_t)DXW * DI;          // DI*64
  ushort_t* dtb   = W_dtb + (size_t)DI * DRNK;         // L*64
  float* dblBC = (float*)(dtb + (size_t)LSEQ * DRNK);  // L*32 f
  float* partial = ws;   // alias (see above)

  // 0) all input casts in one launch
  hipLaunchKernelGGL(cast_all, dim3((CTOT / 4 + 255) / 256), dim3(256), 0, stream,
                     x, W_in, W_out, W_x, W_dt, xb, W_inb, W_outb, W_xb, W_dtb);

  // 1) xrb = bf16(x @ W_in.T)  (M=4096, N=4096, K=1024), 256x128, 512 thr
  hipLaunchKernelGGL(gemm_wide, dim3((2 * DI) / 128, LSEQ / 256), dim3(512), 0, stream,
                     xb, DM, W_inb, DM, xrb, 2 * DI, DM);

  // 2) xsb = bf16(silu(conv(xi) + b)) — sliding window
  hipLaunchKernelGGL(conv2, dim3(LSEQ / 8), dim3(256), 0, stream,
                     xrb, conv_w, conv_b, xsb);

  // 3) partial[z] = xsb @ W_xb.T chunk z; then reduce -> dtb bf16 + dblBC f32
  hipLaunchKernelGGL(gemm_dbl, dim3(1, LSEQ / 128, KSPLIT), dim3(256), 0, stream,
                     xsb, W_xb, partial);
  hipLaunchKernelGGL(reduce_dbl, dim3((LSEQ * DXW) / 256), dim3(256), 0, stream,
                     partial, dtb, dblBC);

  // 4) deltab = bf16(softplus(dtb @ W_dtb.T + b_dt)) — K=64 single-iter 32x32
  hipLaunchKernelGGL(gemm_delta, dim3(DI / 128, LSEQ / 128), dim3(256), 0, stream,
                     dtb, W_dtb, b_dt, deltab);

  // 5) chunked selective scan (3-pass, CLEN=64; sd-compressed carry state)
  hipLaunchKernelGGL(scan_pass1, dim3(DI / 256, NCH), dim3(256), 0, stream,
                     deltab, xsb, dblBC, A_log, sd, cS);
  hipLaunchKernelGGL(scan_pass2, dim3((DI * DSTATE) / 64), dim3(64), 0, stream,
                     sd, cS, A_log, ch0);
  hipLaunchKernelGGL(scan_pass3, dim3(DI / 256, NCH), dim3(256), 0, stream,
                     deltab, xsb, dblBC, A_log, ch0, Dp, xrb, y1b);

  // 6) out = y1b @ W_out.T  (M=4096, N=1024, K=2048), 32x32x16, BK=64
  hipLaunchKernelGGL(HIP_KERNEL_NAME(gemm32<0, 64>),
                     dim3(DM / 64, LSEQ / 128), dim3(256), 0, stream,
                     y1b, DI, W_outb, DI, (void*)out, DM, DI);
}